// Round 5
// baseline (199.216 us; speedup 1.0000x reference)
//
#include <hip/hip_runtime.h>
#include <hip/hip_bf16.h>
#include <math.h>

// Problem constants
#define NB   16      // batch
#define CC   64      // channels
#define ICH  32      // inter channels
#define TV   1600    // T*V = 64*25
#define NTV  (NB*TV) // 25600

typedef __bf16 bf16x8 __attribute__((ext_vector_type(8)));
typedef float  f32x4  __attribute__((ext_vector_type(4)));

// ---------------------------------------------------------------------------
// K1: 1x1 conv projections (all 3 fused per thread -> x read once per og) +
// ChannelGate average fused as blocks 400..463.
// Blocks 0..399: tile = b>>2 (100 tv-tiles of 256), og = b&3 (8 outputs).
// lane<->tv (coalesced x); weights wave-uniform (scalar loads).
//  Qh/Ql = k_x  [N,TV,32]   Kh/Kl = q_x [N,TV,32]   VTh/VTl = v_x^T [N,32,TV]
// ---------------------------------------------------------------------------
__global__ __launch_bounds__(256) void proj_gate_kernel(
    const float* __restrict__ x,
    const float* __restrict__ Wv, const float* __restrict__ bv,
    const float* __restrict__ Wk, const float* __restrict__ bk,
    const float* __restrict__ Wq, const float* __restrict__ bq,
    __bf16* __restrict__ Qh, __bf16* __restrict__ Ql,
    __bf16* __restrict__ Kh, __bf16* __restrict__ Kl,
    __bf16* __restrict__ VTh, __bf16* __restrict__ VTl,
    float* __restrict__ AVG) {
  if (blockIdx.x >= 400) {
    // ---- ChannelGate phase 1: per-(n, c) mean over TV ----
    int b = blockIdx.x - 400;
    int n = b >> 2, cq = b & 3;
    int c16 = threadIdx.x >> 4, l = threadIdx.x & 15;
    int c = cq * 16 + c16;
    const float4* xp = (const float4*)(x + ((size_t)n * CC + c) * TV) + l;
    float s = 0.f;
#pragma unroll
    for (int i = 0; i < 25; ++i) {
      float4 v = xp[i * 16];
      s += v.x + v.y + v.z + v.w;
    }
#pragma unroll
    for (int off = 8; off >= 1; off >>= 1) s += __shfl_down(s, off, 16);
    if (l == 0) AVG[n * CC + c] = s * (1.0f / (float)TV);
    return;
  }

  int tile = blockIdx.x >> 2;
  int og   = blockIdx.x & 3;
  int ob = og * 8;
  int tvIdx = tile * 256 + threadIdx.x;   // 0..25599
  int n = tvIdx / TV, tv = tvIdx % TV;

  float av[8], ak[8], aq[8];
#pragma unroll
  for (int j = 0; j < 8; ++j) { av[j] = bv[ob+j]; ak[j] = bk[ob+j]; aq[j] = bq[ob+j]; }

  const float* xp = x + (size_t)n * CC * TV + tv;
#pragma unroll 8
  for (int c = 0; c < CC; ++c) {
    float xc = xp[c * TV];
#pragma unroll
    for (int j = 0; j < 8; ++j) {
      av[j] = fmaf(Wv[(ob + j) * CC + c], xc, av[j]);
      ak[j] = fmaf(Wk[(ob + j) * CC + c], xc, ak[j]);
      aq[j] = fmaf(Wq[(ob + j) * CC + c], xc, aq[j]);
    }
  }

  // k_x -> Q rows, q_x -> K rows (bf16x8), v_x -> VT scatter
  bf16x8 hh, ll;
#pragma unroll
  for (int j = 0; j < 8; ++j) {
    __bf16 h = (__bf16)ak[j];
    hh[j] = h; ll[j] = (__bf16)(ak[j] - (float)h);
  }
  size_t base = ((size_t)(n * TV + tv)) * ICH + ob;
  *(bf16x8*)(Qh + base) = hh;
  *(bf16x8*)(Ql + base) = ll;
#pragma unroll
  for (int j = 0; j < 8; ++j) {
    __bf16 h = (__bf16)aq[j];
    hh[j] = h; ll[j] = (__bf16)(aq[j] - (float)h);
  }
  *(bf16x8*)(Kh + base) = hh;
  *(bf16x8*)(Kl + base) = ll;
#pragma unroll
  for (int j = 0; j < 8; ++j) {
    int o = ob + j;
    __bf16 h = (__bf16)av[j];
    size_t idx = ((size_t)(n * ICH + o)) * TV + tv;
    VTh[idx] = h;
    VTl[idx] = (__bf16)(av[j] - (float)h);
  }
}

// ---------------------------------------------------------------------------
// K3: MFMA flash attention, split-bf16 (hi/lo). 4 waves/block, private LDS
// Pbuf slices, no intra-loop barriers. XCD-AWARE SWIZZLE: blocks of the same
// batch n land on one XCD residue class (2 batches/XCD -> 0.8 MB << 4 MB L2),
// so K/V re-reads hit per-XCD L2 instead of thrashing to Infinity Cache.
// V-fragments prefetched above the LDS wait. Grid = N*100. P:[N,TV,32] fp32.
// ---------------------------------------------------------------------------
__global__ __launch_bounds__(256) void attn_kernel(
    const __bf16* __restrict__ Qh, const __bf16* __restrict__ Ql,
    const __bf16* __restrict__ Kh, const __bf16* __restrict__ Kl,
    const __bf16* __restrict__ VTh, const __bf16* __restrict__ VTl,
    float* __restrict__ P) {
  __shared__ float lds[4 * 16 * 68];   // 17408 B: per-wave 16x68 Pbuf slice
  // XCD swizzle: consecutive blockIdx round-robin across 8 XCDs.
  // residue r owns batches {2r, 2r+1}.
  int b = blockIdx.x;
  int r8 = b & 7, qq = b >> 3;             // qq in [0,200)
  int n = r8 * 2 + (qq >= 100 ? 1 : 0);
  int rowTile = (qq >= 100) ? qq - 100 : qq;
  int row0 = rowTile * 16;

  int w = threadIdx.x >> 6;
  int lane = threadIdx.x & 63;
  int m = lane & 15, q = lane >> 4;

  float* Pw = lds + w * 1088;          // this wave's 16x68 buffer

  size_t qbase = ((size_t)(n * TV + row0 + m)) * ICH + q * 8;
  bf16x8 aQh = *(const bf16x8*)(Qh + qbase);
  bf16x8 aQl = *(const bf16x8*)(Ql + qbase);

  f32x4 o0 = {0.f, 0.f, 0.f, 0.f};
  f32x4 o1 = {0.f, 0.f, 0.f, 0.f};
  float lsum = 0.f;

  int nch = (w == 3) ? 7 : 6;          // wave w does chunks {4j + (3-w)}
  for (int j = 0; j < nch; ++j) {
    int ch = 4 * j + (3 - w);
    int s0 = ch * 64;
    // ---- QK^T: 4 subtiles of 16 s; 3 MFMAs each (split hi/lo) ----
#pragma unroll
    for (int st = 0; st < 4; ++st) {
      size_t kbase = ((size_t)(n * TV + s0 + st * 16 + m)) * ICH + q * 8;
      bf16x8 bKh = *(const bf16x8*)(Kh + kbase);
      bf16x8 bKl = *(const bf16x8*)(Kl + kbase);
      f32x4 acc = {0.f, 0.f, 0.f, 0.f};
      acc = __builtin_amdgcn_mfma_f32_16x16x32_bf16(aQh, bKh, acc, 0, 0, 0);
      acc = __builtin_amdgcn_mfma_f32_16x16x32_bf16(aQh, bKl, acc, 0, 0, 0);
      acc = __builtin_amdgcn_mfma_f32_16x16x32_bf16(aQl, bKh, acc, 0, 0, 0);
      // C layout: row = q*4+r, col = st*16+m
#pragma unroll
      for (int rr = 0; rr < 4; ++rr)
        Pw[(q * 4 + rr) * 68 + st * 16 + m] = __expf(acc[rr]);
    }
    // Prefetch ALL PV V-fragments BEFORE the LDS wait (independent of LDS) --
    // keeps the L2 round-trip off the post-wait critical path.
    bf16x8 pVh[2][2], pVl[2][2];
#pragma unroll
    for (int kc = 0; kc < 2; ++kc)
#pragma unroll
      for (int ict = 0; ict < 2; ++ict) {
        size_t vbase = ((size_t)(n * ICH + ict * 16 + m)) * TV + s0 + kc * 32 + q * 8;
        pVh[kc][ict] = *(const bf16x8*)(VTh + vbase);
        pVl[kc][ict] = *(const bf16x8*)(VTl + vbase);
      }
    // in-wave DS write->read ordering (cross-lane, same wave)
    asm volatile("s_waitcnt lgkmcnt(0)" ::: "memory");
    // ---- P*V: 2 k-chunks of 32 s; A-frag from own LDS slice ----
#pragma unroll
    for (int kc = 0; kc < 2; ++kc) {
      const f32x4* prow = (const f32x4*)(Pw + m * 68 + kc * 32);
      f32x4 pa = prow[q * 2];
      f32x4 pb = prow[q * 2 + 1];
      float pv[8] = {pa.x, pa.y, pa.z, pa.w, pb.x, pb.y, pb.z, pb.w};
      bf16x8 aPh, aPl;
#pragma unroll
      for (int jj = 0; jj < 8; ++jj) {
        lsum += pv[jj];
        __bf16 h = (__bf16)pv[jj];
        aPh[jj] = h;
        aPl[jj] = (__bf16)(pv[jj] - (float)h);
      }
#pragma unroll
      for (int ict = 0; ict < 2; ++ict) {
        f32x4 acc = (ict == 0) ? o0 : o1;
        acc = __builtin_amdgcn_mfma_f32_16x16x32_bf16(aPh, pVh[kc][ict], acc, 0, 0, 0);
        acc = __builtin_amdgcn_mfma_f32_16x16x32_bf16(aPh, pVl[kc][ict], acc, 0, 0, 0);
        acc = __builtin_amdgcn_mfma_f32_16x16x32_bf16(aPl, pVh[kc][ict], acc, 0, 0, 0);
        if (ict == 0) o0 = acc; else o1 = acc;
      }
    }
    // keep next iteration's DS writes behind this iteration's DS reads
    asm volatile("" ::: "memory");
  }

  // wave-local row sums: lane(m,q) -> row m total for this wave's s-subset
  lsum += __shfl_xor(lsum, 16, 64);
  lsum += __shfl_xor(lsum, 32, 64);

  // ---- merge 4 wave-partials through LDS (reuse Pbuf area) ----
  __syncthreads();                      // all waves done with their Pbuf
  float* mp = lds + (w * 64 + lane) * 9;  // 2304 floats used
#pragma unroll
  for (int rr = 0; rr < 4; ++rr) { mp[rr] = o0[rr]; mp[4 + rr] = o1[rr]; }
  mp[8] = lsum;
  __syncthreads();
  if (w == 0) {
#pragma unroll
    for (int ww = 1; ww < 4; ++ww) {
      const float* sp = lds + (ww * 64 + lane) * 9;
#pragma unroll
      for (int rr = 0; rr < 4; ++rr) { o0[rr] += sp[rr]; o1[rr] += sp[4 + rr]; }
      lsum += sp[8];
    }
#pragma unroll
    for (int rr = 0; rr < 4; ++rr) {
      float lr = __shfl(lsum, q * 4 + rr, 64);   // lane (q*4+rr): row total
      float inv = 1.f / lr;
      size_t pb = ((size_t)(n * TV + row0 + q * 4 + rr)) * ICH;
      P[pb + m]      = o0[rr] * inv;
      P[pb + 16 + m] = o1[rr] * inv;
    }
  }
}

// ---------------------------------------------------------------------------
// K4: trans-conv recompute + BN partial sums. Grid 800 = cg(8 ch)*100 + tb.
// PS2[800][16] = {sum_y[8], sum_y2[8]}.
// ---------------------------------------------------------------------------
__global__ __launch_bounds__(256) void stats_kernel(
    const float* __restrict__ P, const float* __restrict__ Wt,
    const float* __restrict__ bt, float* __restrict__ PS2) {
  int cg = blockIdx.x / 100;
  int tb = blockIdx.x % 100;
  int tvIdx = tb * 256 + threadIdx.x;
  int n = tvIdx / TV, tv = tvIdx % TV;

  union { f32x4 v[8]; float f[32]; } p;
  const f32x4* pp = (const f32x4*)(P + ((size_t)(n * TV + tv)) * ICH);
#pragma unroll
  for (int u = 0; u < 8; ++u) p.v[u] = pp[u];

  __shared__ float red[2][4][8];
  int w = threadIdx.x >> 6, lane = threadIdx.x & 63;
#pragma unroll
  for (int j = 0; j < 8; ++j) {
    int c = cg * 8 + j;
    float y = bt[c];
#pragma unroll
    for (int i = 0; i < ICH; ++i) y = fmaf(Wt[c * ICH + i], p.f[i], y);
    float y2 = y * y;
#pragma unroll
    for (int off = 32; off >= 1; off >>= 1) {
      y  += __shfl_xor(y,  off, 64);
      y2 += __shfl_xor(y2, off, 64);
    }
    if (lane == 0) { red[0][w][j] = y; red[1][w][j] = y2; }
  }
  __syncthreads();
  if (threadIdx.x < 16) {
    int which = threadIdx.x >> 3, j = threadIdx.x & 7;
    float s = red[which][0][j] + red[which][1][j] +
              red[which][2][j] + red[which][3][j];
    PS2[blockIdx.x * 16 + which * 8 + j] = s;
  }
}

// ---------------------------------------------------------------------------
// K5: finalize BN stats -> SS, plus ChannelGate MLP -> GATE.
// 1 block, 128 threads. AVG lives in d_out (overwritten later by apply).
// ---------------------------------------------------------------------------
__global__ __launch_bounds__(128) void finalize_stats(
    const float* __restrict__ PS2, const float* __restrict__ gamma,
    const float* __restrict__ beta, const float* __restrict__ AVG,
    const float* __restrict__ W1, const float* __restrict__ b1,
    const float* __restrict__ W2, const float* __restrict__ b2,
    float* __restrict__ SS, float* __restrict__ GATE) {
  int t = threadIdx.x;
  __shared__ float sh[NB][4];
  if (t < 64) {
    int c = t, cg = c >> 3, j = c & 7;
    float s = 0.f, ss = 0.f;
    for (int b = 0; b < 100; ++b) {
      int base = (cg * 100 + b) * 16;
      s  += PS2[base + j];
      ss += PS2[base + 8 + j];
    }
    float mean = s * (1.f / (float)NTV);
    float var  = ss * (1.f / (float)NTV) - mean * mean;
    float scale = rsqrtf(var + 1e-5f) * gamma[c];
    SS[c] = scale;
    SS[64 + c] = beta[c] - mean * scale;
    // MLP hidden: t -> (n = t>>2, jj = t&3)
    int n = t >> 2, jj = t & 3;
    float h = b1[jj];
    for (int c2 = 0; c2 < CC; ++c2)
      h = fmaf(W1[jj * CC + c2], AVG[n * CC + c2], h);
    sh[n][jj] = fmaxf(h, 0.f);
  }
  __syncthreads();
#pragma unroll
  for (int u = 0; u < 8; ++u) {
    int idx = t * 8 + u;
    int n = idx >> 6, c = idx & 63;
    float g = b2[c];
#pragma unroll
    for (int jj = 0; jj < 4; ++jj) g = fmaf(W2[c * 4 + jj], sh[n][jj], g);
    GATE[idx] = 1.f / (1.f + __expf(-g));
  }
}

// ---------------------------------------------------------------------------
// K6: recompute y for 8 channels, apply BN + gate + residual. Grid 800.
// ---------------------------------------------------------------------------
__global__ __launch_bounds__(256) void apply_kernel(
    const float* __restrict__ P, const float* __restrict__ Wt,
    const float* __restrict__ bt, const float* __restrict__ SS,
    const float* __restrict__ gate, const float* __restrict__ x,
    float* __restrict__ out) {
  int cg = blockIdx.x / 100;
  int tb = blockIdx.x % 100;
  int tvIdx = tb * 256 + threadIdx.x;
  int n = tvIdx / TV, tv = tvIdx % TV;

  union { f32x4 v[8]; float f[32]; } p;
  const f32x4* pp = (const f32x4*)(P + ((size_t)(n * TV + tv)) * ICH);
#pragma unroll
  for (int u = 0; u < 8; ++u) p.v[u] = pp[u];

#pragma unroll
  for (int j = 0; j < 8; ++j) {
    int c = cg * 8 + j;
    float y = bt[c];
#pragma unroll
    for (int i = 0; i < ICH; ++i) y = fmaf(Wt[c * ICH + i], p.f[i], y);
    size_t idx = ((size_t)(n * CC + c)) * TV + tv;
    out[idx] = gate[n * CC + c] * fmaf(y, SS[c], SS[64 + c]) + x[idx];
  }
}

// ---------------------------------------------------------------------------
extern "C" void kernel_launch(void* const* d_in, const int* in_sizes, int n_in,
                              void* d_out, int out_size, void* d_ws, size_t ws_size,
                              hipStream_t stream) {
  const float* x     = (const float*)d_in[0];
  const float* Wv    = (const float*)d_in[1];
  const float* bv    = (const float*)d_in[2];
  const float* Wk    = (const float*)d_in[3];
  const float* bk    = (const float*)d_in[4];
  const float* Wq    = (const float*)d_in[5];
  const float* bq    = (const float*)d_in[6];
  const float* Wt    = (const float*)d_in[7];
  const float* bt    = (const float*)d_in[8];
  const float* gamma = (const float*)d_in[9];
  const float* beta  = (const float*)d_in[10];
  const float* W1    = (const float*)d_in[11];
  const float* b1    = (const float*)d_in[12];
  const float* W2    = (const float*)d_in[13];
  const float* b2    = (const float*)d_in[14];
  float* out = (float*)d_out;
  char* ws = (char*)d_ws;

  // workspace layout (bytes) — total 13,163,008 B (same as rounds 1-4, fits)
  const size_t E = 819200;
  __bf16* Qh  = (__bf16*)(ws);
  __bf16* Ql  = (__bf16*)(ws + 2*E);
  __bf16* Kh  = (__bf16*)(ws + 4*E);
  __bf16* Kl  = (__bf16*)(ws + 6*E);
  __bf16* VTh = (__bf16*)(ws + 8*E);
  __bf16* VTl = (__bf16*)(ws + 10*E);
  float*  P   = (float*) (ws + 12*E);                    // 819200 floats
  float*  PS2 = (float*) (ws + 12*E + 4*E);              // 12800 floats
  float*  SS  = (float*) (ws + 12*E + 4*E + 51200);      // 128 floats
  float*  GATE= (float*) (ws + 12*E + 4*E + 51200 + 512);// 1024 floats
  float*  AVG = out;   // scratch: fully overwritten by apply_kernel at the end

  proj_gate_kernel<<<464, 256, 0, stream>>>(x, Wv, bv, Wk, bk, Wq, bq,
                                            Qh, Ql, Kh, Kl, VTh, VTl, AVG);
  attn_kernel<<<NB * 100, 256, 0, stream>>>(Qh, Ql, Kh, Kl, VTh, VTl, P);
  stats_kernel<<<800, 256, 0, stream>>>(P, Wt, bt, PS2);
  finalize_stats<<<1, 128, 0, stream>>>(PS2, gamma, beta, AVG,
                                        W1, b1, W2, b2, SS, GATE);
  apply_kernel<<<800, 256, 0, stream>>>(P, Wt, bt, SS, GATE, x, out);
}

// Round 6
// 158.625 us; speedup vs baseline: 1.2559x; 1.2559x over previous
//
#include <hip/hip_runtime.h>
#include <hip/hip_bf16.h>
#include <math.h>

// Problem constants
#define NB   16      // batch
#define CC   64      // channels
#define ICH  32      // inter channels
#define TV   1600    // T*V = 64*25
#define NTV  (NB*TV) // 25600

typedef __bf16 bf16x8 __attribute__((ext_vector_type(8)));
typedef float  f32x4  __attribute__((ext_vector_type(4)));

// ---------------------------------------------------------------------------
// K1: 1x1 conv projections (3 fused; x read once per og) + ChannelGate avg
// fused as blocks 400..463. Plain bf16 outputs (no hi/lo split).
//  Qb = k_x [N,TV,32]   Kb = q_x [N,TV,32]   VTb = v_x^T [N,32,TV]
// ---------------------------------------------------------------------------
__global__ __launch_bounds__(256) void proj_gate_kernel(
    const float* __restrict__ x,
    const float* __restrict__ Wv, const float* __restrict__ bv,
    const float* __restrict__ Wk, const float* __restrict__ bk,
    const float* __restrict__ Wq, const float* __restrict__ bq,
    __bf16* __restrict__ Qb, __bf16* __restrict__ Kb,
    __bf16* __restrict__ VTb, float* __restrict__ AVG) {
  if (blockIdx.x >= 400) {
    // ---- ChannelGate phase 1: per-(n, c) mean over TV ----
    int b = blockIdx.x - 400;
    int n = b >> 2, cq = b & 3;
    int c16 = threadIdx.x >> 4, l = threadIdx.x & 15;
    int c = cq * 16 + c16;
    const float4* xp = (const float4*)(x + ((size_t)n * CC + c) * TV) + l;
    float s = 0.f;
#pragma unroll
    for (int i = 0; i < 25; ++i) {
      float4 v = xp[i * 16];
      s += v.x + v.y + v.z + v.w;
    }
#pragma unroll
    for (int off = 8; off >= 1; off >>= 1) s += __shfl_down(s, off, 16);
    if (l == 0) AVG[n * CC + c] = s * (1.0f / (float)TV);
    return;
  }

  int tile = blockIdx.x >> 2;
  int og   = blockIdx.x & 3;
  int ob = og * 8;
  int tvIdx = tile * 256 + threadIdx.x;   // 0..25599
  int n = tvIdx / TV, tv = tvIdx % TV;

  float av[8], ak[8], aq[8];
#pragma unroll
  for (int j = 0; j < 8; ++j) { av[j] = bv[ob+j]; ak[j] = bk[ob+j]; aq[j] = bq[ob+j]; }

  const float* xp = x + (size_t)n * CC * TV + tv;
#pragma unroll 8
  for (int c = 0; c < CC; ++c) {
    float xc = xp[c * TV];
#pragma unroll
    for (int j = 0; j < 8; ++j) {
      av[j] = fmaf(Wv[(ob + j) * CC + c], xc, av[j]);
      ak[j] = fmaf(Wk[(ob + j) * CC + c], xc, ak[j]);
      aq[j] = fmaf(Wq[(ob + j) * CC + c], xc, aq[j]);
    }
  }

  bf16x8 t;
#pragma unroll
  for (int j = 0; j < 8; ++j) t[j] = (__bf16)ak[j];
  int base = (n * TV + tv) * ICH + ob;
  *(bf16x8*)(Qb + base) = t;                 // k_x -> attention rows
#pragma unroll
  for (int j = 0; j < 8; ++j) t[j] = (__bf16)aq[j];
  *(bf16x8*)(Kb + base) = t;                 // q_x -> attention cols
#pragma unroll
  for (int j = 0; j < 8; ++j)                // v_x -> transposed
    VTb[(n * ICH + ob + j) * TV + tv] = (__bf16)av[j];
}

// ---------------------------------------------------------------------------
// K3: MFMA flash attention, plain bf16. 4 waves/block; 32 rows/block (two
// 16-row m-tiles per wave, sharing every K/V fragment -> 2x MFMA per load +
// in-wave ILP). Each wave covers 1/4 of the 25 s-chunks with a private LDS
// Pbuf (no intra-loop barriers; compiler free to prefetch next chunk's
// loads during PV). XCD swizzle: batch n pinned to one XCD residue class.
// Grid = NB*50 = 800. P:[N,TV,32] fp32 normalized.
// ---------------------------------------------------------------------------
__global__ __launch_bounds__(256) void attn_kernel(
    const __bf16* __restrict__ Qb, const __bf16* __restrict__ Kb,
    const __bf16* __restrict__ VTb, float* __restrict__ P) {
  __shared__ float lds[4 * 2 * 16 * 68];   // 34816 B
  int b = blockIdx.x;
  int r8 = b & 7, qq = b >> 3;             // qq in [0,100)
  int n = r8 * 2 + (qq >= 50 ? 1 : 0);
  int rowTile = (qq >= 50) ? qq - 50 : qq;
  int row0 = rowTile * 32;

  int w = threadIdx.x >> 6;
  int lane = threadIdx.x & 63;
  int m = lane & 15, q = lane >> 4;

  float* Pw0 = lds + w * 2176;             // m-tile 0: 16x68
  float* Pw1 = Pw0 + 1088;                 // m-tile 1: 16x68

  const __bf16* Qn = Qb  + (size_t)n * TV * ICH;
  const __bf16* Kn = Kb  + (size_t)n * TV * ICH;
  const __bf16* Vn = VTb + (size_t)n * ICH * TV;

  bf16x8 aQ0 = *(const bf16x8*)(Qn + (row0 + m) * ICH + q * 8);
  bf16x8 aQ1 = *(const bf16x8*)(Qn + (row0 + 16 + m) * ICH + q * 8);

  f32x4 o00 = {0.f,0.f,0.f,0.f}, o01 = {0.f,0.f,0.f,0.f};
  f32x4 o10 = {0.f,0.f,0.f,0.f}, o11 = {0.f,0.f,0.f,0.f};
  float ls0 = 0.f, ls1 = 0.f;
  const f32x4 zero = {0.f,0.f,0.f,0.f};

  int nch = (w == 3) ? 7 : 6;              // wave w: chunks {4j + (3-w)}
  for (int j = 0; j < nch; ++j) {
    int s0 = (4 * j + (3 - w)) * 64;
    // ---- QK^T: 4 subtiles of 16 s; 1 MFMA per m-tile (shared bK) ----
#pragma unroll
    for (int st = 0; st < 4; ++st) {
      bf16x8 bK = *(const bf16x8*)(Kn + (s0 + st * 16 + m) * ICH + q * 8);
      f32x4 a0 = __builtin_amdgcn_mfma_f32_16x16x32_bf16(aQ0, bK, zero, 0, 0, 0);
      f32x4 a1 = __builtin_amdgcn_mfma_f32_16x16x32_bf16(aQ1, bK, zero, 0, 0, 0);
      // C layout: row = q*4+r, col = st*16+m
#pragma unroll
      for (int r = 0; r < 4; ++r) {
        Pw0[(q * 4 + r) * 68 + st * 16 + m] = __expf(a0[r]);
        Pw1[(q * 4 + r) * 68 + st * 16 + m] = __expf(a1[r]);
      }
    }
    // in-wave DS write->read ordering (cross-lane, same wave)
    asm volatile("s_waitcnt lgkmcnt(0)" ::: "memory");
    // ---- P*V: 2 k-chunks of 32 s; A-frags from own LDS, shared bV ----
#pragma unroll
    for (int kc = 0; kc < 2; ++kc) {
      const f32x4* pr0 = (const f32x4*)(Pw0 + m * 68 + kc * 32);
      const f32x4* pr1 = (const f32x4*)(Pw1 + m * 68 + kc * 32);
      f32x4 p0a = pr0[q * 2], p0b = pr0[q * 2 + 1];
      f32x4 p1a = pr1[q * 2], p1b = pr1[q * 2 + 1];
      bf16x8 aP0, aP1;
#pragma unroll
      for (int r = 0; r < 4; ++r) {
        ls0 += p0a[r] + p0b[r];
        ls1 += p1a[r] + p1b[r];
        aP0[r]     = (__bf16)p0a[r];
        aP0[4 + r] = (__bf16)p0b[r];
        aP1[r]     = (__bf16)p1a[r];
        aP1[4 + r] = (__bf16)p1b[r];
      }
#pragma unroll
      for (int ict = 0; ict < 2; ++ict) {
        bf16x8 bV = *(const bf16x8*)(Vn + (ict * 16 + m) * TV + s0 + kc * 32 + q * 8);
        if (ict == 0) {
          o00 = __builtin_amdgcn_mfma_f32_16x16x32_bf16(aP0, bV, o00, 0, 0, 0);
          o10 = __builtin_amdgcn_mfma_f32_16x16x32_bf16(aP1, bV, o10, 0, 0, 0);
        } else {
          o01 = __builtin_amdgcn_mfma_f32_16x16x32_bf16(aP0, bV, o01, 0, 0, 0);
          o11 = __builtin_amdgcn_mfma_f32_16x16x32_bf16(aP1, bV, o11, 0, 0, 0);
        }
      }
    }
    // NOTE: no end-of-loop clobber -- compiler may prefetch next chunk's
    // K/V loads into this chunk's PV section. Pbuf WAR is safe: DS ops are
    // in-order per wave and the compiler won't reorder aliasing DS ops.
  }

  // wave-local row sums: lane(m,q) -> row m total for this wave's s-subset
  ls0 += __shfl_xor(ls0, 16, 64); ls0 += __shfl_xor(ls0, 32, 64);
  ls1 += __shfl_xor(ls1, 16, 64); ls1 += __shfl_xor(ls1, 32, 64);

  // ---- merge 4 wave-partials through LDS (reuse Pbuf area) ----
  __syncthreads();                         // all waves done with their Pbuf
  float* mp = lds + (w * 64 + lane) * 18;  // 4608 floats used (< 8704)
#pragma unroll
  for (int r = 0; r < 4; ++r) {
    mp[r]      = o00[r]; mp[4 + r]  = o01[r];
    mp[8 + r]  = o10[r]; mp[12 + r] = o11[r];
  }
  mp[16] = ls0; mp[17] = ls1;
  __syncthreads();
  if (w == 0) {
#pragma unroll
    for (int ww = 1; ww < 4; ++ww) {
      const float* sp = lds + (ww * 64 + lane) * 18;
#pragma unroll
      for (int r = 0; r < 4; ++r) {
        o00[r] += sp[r];      o01[r] += sp[4 + r];
        o10[r] += sp[8 + r];  o11[r] += sp[12 + r];
      }
      ls0 += sp[16]; ls1 += sp[17];
    }
#pragma unroll
    for (int r = 0; r < 4; ++r) {
      float lr0 = __shfl(ls0, q * 4 + r, 64);
      float lr1 = __shfl(ls1, q * 4 + r, 64);
      float i0 = 1.f / lr0, i1 = 1.f / lr1;
      int pb0 = (n * TV + row0 + q * 4 + r) * ICH;
      int pb1 = pb0 + 16 * ICH;
      P[pb0 + m]      = o00[r] * i0;
      P[pb0 + 16 + m] = o01[r] * i0;
      P[pb1 + m]      = o10[r] * i1;
      P[pb1 + 16 + m] = o11[r] * i1;
    }
  }
}

// ---------------------------------------------------------------------------
// K4: trans-conv recompute + BN partial sums. Grid 800 = cg(8 ch)*100 + tb.
// PS2[800][16] = {sum_y[8], sum_y2[8]}.
// ---------------------------------------------------------------------------
__global__ __launch_bounds__(256) void stats_kernel(
    const float* __restrict__ P, const float* __restrict__ Wt,
    const float* __restrict__ bt, float* __restrict__ PS2) {
  int cg = blockIdx.x / 100;
  int tb = blockIdx.x % 100;
  int tvIdx = tb * 256 + threadIdx.x;
  int n = tvIdx / TV, tv = tvIdx % TV;

  union { f32x4 v[8]; float f[32]; } p;
  const f32x4* pp = (const f32x4*)(P + ((size_t)(n * TV + tv)) * ICH);
#pragma unroll
  for (int u = 0; u < 8; ++u) p.v[u] = pp[u];

  __shared__ float red[2][4][8];
  int w = threadIdx.x >> 6, lane = threadIdx.x & 63;
#pragma unroll
  for (int j = 0; j < 8; ++j) {
    int c = cg * 8 + j;
    float y = bt[c];
#pragma unroll
    for (int i = 0; i < ICH; ++i) y = fmaf(Wt[c * ICH + i], p.f[i], y);
    float y2 = y * y;
#pragma unroll
    for (int off = 32; off >= 1; off >>= 1) {
      y  += __shfl_xor(y,  off, 64);
      y2 += __shfl_xor(y2, off, 64);
    }
    if (lane == 0) { red[0][w][j] = y; red[1][w][j] = y2; }
  }
  __syncthreads();
  if (threadIdx.x < 16) {
    int which = threadIdx.x >> 3, j = threadIdx.x & 7;
    float s = red[which][0][j] + red[which][1][j] +
              red[which][2][j] + red[which][3][j];
    PS2[blockIdx.x * 16 + which * 8 + j] = s;
  }
}

// ---------------------------------------------------------------------------
// K5: finalize BN stats -> SS, plus ChannelGate MLP -> GATE.
// 1 block, 128 threads. AVG lives in d_out (overwritten later by apply).
// ---------------------------------------------------------------------------
__global__ __launch_bounds__(128) void finalize_stats(
    const float* __restrict__ PS2, const float* __restrict__ gamma,
    const float* __restrict__ beta, const float* __restrict__ AVG,
    const float* __restrict__ W1, const float* __restrict__ b1,
    const float* __restrict__ W2, const float* __restrict__ b2,
    float* __restrict__ SS, float* __restrict__ GATE) {
  int t = threadIdx.x;
  __shared__ float sh[NB][4];
  if (t < 64) {
    int c = t, cg = c >> 3, j = c & 7;
    float s = 0.f, ss = 0.f;
    for (int b = 0; b < 100; ++b) {
      int base = (cg * 100 + b) * 16;
      s  += PS2[base + j];
      ss += PS2[base + 8 + j];
    }
    float mean = s * (1.f / (float)NTV);
    float var  = ss * (1.f / (float)NTV) - mean * mean;
    float scale = rsqrtf(var + 1e-5f) * gamma[c];
    SS[c] = scale;
    SS[64 + c] = beta[c] - mean * scale;
    // MLP hidden: t -> (n = t>>2, jj = t&3)
    int n = t >> 2, jj = t & 3;
    float h = b1[jj];
    for (int c2 = 0; c2 < CC; ++c2)
      h = fmaf(W1[jj * CC + c2], AVG[n * CC + c2], h);
    sh[n][jj] = fmaxf(h, 0.f);
  }
  __syncthreads();
#pragma unroll
  for (int u = 0; u < 8; ++u) {
    int idx = t * 8 + u;
    int n = idx >> 6, c = idx & 63;
    float g = b2[c];
#pragma unroll
    for (int jj = 0; jj < 4; ++jj) g = fmaf(W2[c * 4 + jj], sh[n][jj], g);
    GATE[idx] = 1.f / (1.f + __expf(-g));
  }
}

// ---------------------------------------------------------------------------
// K6: recompute y for 8 channels, apply BN + gate + residual. Grid 800.
// ---------------------------------------------------------------------------
__global__ __launch_bounds__(256) void apply_kernel(
    const float* __restrict__ P, const float* __restrict__ Wt,
    const float* __restrict__ bt, const float* __restrict__ SS,
    const float* __restrict__ gate, const float* __restrict__ x,
    float* __restrict__ out) {
  int cg = blockIdx.x / 100;
  int tb = blockIdx.x % 100;
  int tvIdx = tb * 256 + threadIdx.x;
  int n = tvIdx / TV, tv = tvIdx % TV;

  union { f32x4 v[8]; float f[32]; } p;
  const f32x4* pp = (const f32x4*)(P + ((size_t)(n * TV + tv)) * ICH);
#pragma unroll
  for (int u = 0; u < 8; ++u) p.v[u] = pp[u];

#pragma unroll
  for (int j = 0; j < 8; ++j) {
    int c = cg * 8 + j;
    float y = bt[c];
#pragma unroll
    for (int i = 0; i < ICH; ++i) y = fmaf(Wt[c * ICH + i], p.f[i], y);
    size_t idx = ((size_t)(n * CC + c)) * TV + tv;
    out[idx] = gate[n * CC + c] * fmaf(y, SS[c], SS[64 + c]) + x[idx];
  }
}

// ---------------------------------------------------------------------------
extern "C" void kernel_launch(void* const* d_in, const int* in_sizes, int n_in,
                              void* d_out, int out_size, void* d_ws, size_t ws_size,
                              hipStream_t stream) {
  const float* x     = (const float*)d_in[0];
  const float* Wv    = (const float*)d_in[1];
  const float* bv    = (const float*)d_in[2];
  const float* Wk    = (const float*)d_in[3];
  const float* bk    = (const float*)d_in[4];
  const float* Wq    = (const float*)d_in[5];
  const float* bq    = (const float*)d_in[6];
  const float* Wt    = (const float*)d_in[7];
  const float* bt    = (const float*)d_in[8];
  const float* gamma = (const float*)d_in[9];
  const float* beta  = (const float*)d_in[10];
  const float* W1    = (const float*)d_in[11];
  const float* b1    = (const float*)d_in[12];
  const float* W2    = (const float*)d_in[13];
  const float* b2    = (const float*)d_in[14];
  float* out = (float*)d_out;
  char* ws = (char*)d_ws;

  // workspace layout (bytes) — total ~8.3 MB (< 13.16 MB proven available)
  const size_t E = 819200;                    // N*TV*ICH elements
  __bf16* Qb  = (__bf16*)(ws);                // 2E bytes
  __bf16* Kb  = (__bf16*)(ws + 2*E);          // 2E bytes
  __bf16* VTb = (__bf16*)(ws + 4*E);          // 2E bytes
  float*  P   = (float*) (ws + 6*E);          // 4E bytes
  float*  PS2 = (float*) (ws + 10*E);         // 51200 B
  float*  SS  = (float*) (ws + 10*E + 51200); // 512 B
  float*  GATE= (float*) (ws + 10*E + 51712); // 4096 B
  float*  AVG = out;   // scratch: fully overwritten by apply_kernel

  proj_gate_kernel<<<464, 256, 0, stream>>>(x, Wv, bv, Wk, bk, Wq, bq,
                                            Qb, Kb, VTb, AVG);
  attn_kernel<<<NB * 50, 256, 0, stream>>>(Qb, Kb, VTb, P);
  stats_kernel<<<800, 256, 0, stream>>>(P, Wt, bt, PS2);
  finalize_stats<<<1, 128, 0, stream>>>(PS2, gamma, beta, AVG,
                                        W1, b1, W2, b2, SS, GATE);
  apply_kernel<<<800, 256, 0, stream>>>(P, Wt, bt, SS, GATE, x, out);
}

// Round 7
// 157.406 us; speedup vs baseline: 1.2656x; 1.0077x over previous
//
#include <hip/hip_runtime.h>
#include <hip/hip_bf16.h>
#include <math.h>

// Problem constants
#define NB   16      // batch
#define CC   64      // channels
#define ICH  32      // inter channels
#define TV   1600    // T*V = 64*25
#define NTV  (NB*TV) // 25600

typedef __bf16 bf16x8 __attribute__((ext_vector_type(8)));
typedef float  f32x4  __attribute__((ext_vector_type(4)));

// ---------------------------------------------------------------------------
// K1: 1x1 conv projections (3 fused; x read once per og) + ChannelGate avg
// fused as blocks 400..463. Plain bf16 outputs.
//  Qb = k_x [N,TV,32]   Kb = q_x [N,TV,32]   VTb = v_x^T [N,32,TV]
// ---------------------------------------------------------------------------
__global__ __launch_bounds__(256) void proj_gate_kernel(
    const float* __restrict__ x,
    const float* __restrict__ Wv, const float* __restrict__ bv,
    const float* __restrict__ Wk, const float* __restrict__ bk,
    const float* __restrict__ Wq, const float* __restrict__ bq,
    __bf16* __restrict__ Qb, __bf16* __restrict__ Kb,
    __bf16* __restrict__ VTb, float* __restrict__ AVG) {
  if (blockIdx.x >= 400) {
    int b = blockIdx.x - 400;
    int n = b >> 2, cq = b & 3;
    int c16 = threadIdx.x >> 4, l = threadIdx.x & 15;
    int c = cq * 16 + c16;
    const float4* xp = (const float4*)(x + ((size_t)n * CC + c) * TV) + l;
    float s = 0.f;
#pragma unroll
    for (int i = 0; i < 25; ++i) {
      float4 v = xp[i * 16];
      s += v.x + v.y + v.z + v.w;
    }
#pragma unroll
    for (int off = 8; off >= 1; off >>= 1) s += __shfl_down(s, off, 16);
    if (l == 0) AVG[n * CC + c] = s * (1.0f / (float)TV);
    return;
  }

  int tile = blockIdx.x >> 2;
  int og   = blockIdx.x & 3;
  int ob = og * 8;
  int tvIdx = tile * 256 + threadIdx.x;   // 0..25599
  int n = tvIdx / TV, tv = tvIdx % TV;

  float av[8], ak[8], aq[8];
#pragma unroll
  for (int j = 0; j < 8; ++j) { av[j] = bv[ob+j]; ak[j] = bk[ob+j]; aq[j] = bq[ob+j]; }

  const float* xp = x + (size_t)n * CC * TV + tv;
#pragma unroll 8
  for (int c = 0; c < CC; ++c) {
    float xc = xp[c * TV];
#pragma unroll
    for (int j = 0; j < 8; ++j) {
      av[j] = fmaf(Wv[(ob + j) * CC + c], xc, av[j]);
      ak[j] = fmaf(Wk[(ob + j) * CC + c], xc, ak[j]);
      aq[j] = fmaf(Wq[(ob + j) * CC + c], xc, aq[j]);
    }
  }

  bf16x8 t;
#pragma unroll
  for (int j = 0; j < 8; ++j) t[j] = (__bf16)ak[j];
  int base = (n * TV + tv) * ICH + ob;
  *(bf16x8*)(Qb + base) = t;                 // k_x -> attention rows
#pragma unroll
  for (int j = 0; j < 8; ++j) t[j] = (__bf16)aq[j];
  *(bf16x8*)(Kb + base) = t;                 // q_x -> attention cols
#pragma unroll
  for (int j = 0; j < 8; ++j)                // v_x -> transposed
    VTb[(n * ICH + ob + j) * TV + tv] = (__bf16)av[j];
}

// ---------------------------------------------------------------------------
// K3: MFMA flash attention, bf16, SOFTWARE-PIPELINED 2 chunks deep.
// 4 waves/block, 32 rows/block (2 m-tiles/wave, shared K/V fragments).
// Per wave: 2 LDS Pbuf slices (bf16, stride 72 -> 16B-aligned b128 reads);
// loop does QK(A), QK(B), one lgkmcnt(0), PV(A), PV(B) -- chunk B's loads
// and MFMAs hide chunk A's exp/LDS latency. Row sums accumulated in f32 in
// C-layout at exp time (no f32 LDS round-trip). No intra-loop barriers.
// XCD swizzle pins each batch to one XCD residue class. Grid = NB*50 = 800.
// ---------------------------------------------------------------------------
__global__ __launch_bounds__(256) void attn_kernel(
    const __bf16* __restrict__ Qb, const __bf16* __restrict__ Kb,
    const __bf16* __restrict__ VTb, float* __restrict__ P) {
  // per wave: 2 slices x 2 tiles x (16 rows x 72) bf16 = 4608 bf16 = 9216 B
  __shared__ __bf16 lds[4 * 4608];           // 36864 B total
  int b = blockIdx.x;
  int r8 = b & 7, qq = b >> 3;               // qq in [0,100)
  int n = r8 * 2 + (qq >= 50 ? 1 : 0);
  int rowTile = (qq >= 50) ? qq - 50 : qq;
  int row0 = rowTile * 32;

  int w = threadIdx.x >> 6;
  int lane = threadIdx.x & 63;
  int m = lane & 15, q = lane >> 4;

  __bf16* Pw = lds + w * 4608;               // [slice][tile][16][72]

  const __bf16* Qn = Qb  + (size_t)n * TV * ICH;
  const __bf16* Kn = Kb  + (size_t)n * TV * ICH;
  const __bf16* Vn = VTb + (size_t)n * ICH * TV;

  bf16x8 aQ0 = *(const bf16x8*)(Qn + (row0 + m) * ICH + q * 8);
  bf16x8 aQ1 = *(const bf16x8*)(Qn + (row0 + 16 + m) * ICH + q * 8);

  f32x4 o00 = {0.f,0.f,0.f,0.f}, o01 = {0.f,0.f,0.f,0.f};
  f32x4 o10 = {0.f,0.f,0.f,0.f}, o11 = {0.f,0.f,0.f,0.f};
  f32x4 ls0 = {0.f,0.f,0.f,0.f}, ls1 = {0.f,0.f,0.f,0.f};
  const f32x4 zero = {0.f,0.f,0.f,0.f};

  int nch = (w == 3) ? 7 : 6;                // wave w: chunks {4j + (3-w)}

  for (int jj = 0; jj < nch; jj += 2) {
    int sA = (4 * jj + (3 - w)) * 64;
    bool hasB = (jj + 1) < nch;
    int sB = hasB ? (4 * (jj + 1) + (3 - w)) * 64 : sA;

    // ---- QK chunk A -> slice 0 ----
#pragma unroll
    for (int st = 0; st < 4; ++st) {
      bf16x8 bK = *(const bf16x8*)(Kn + (sA + st * 16 + m) * ICH + q * 8);
      f32x4 a0 = __builtin_amdgcn_mfma_f32_16x16x32_bf16(aQ0, bK, zero, 0, 0, 0);
      f32x4 a1 = __builtin_amdgcn_mfma_f32_16x16x32_bf16(aQ1, bK, zero, 0, 0, 0);
#pragma unroll
      for (int r = 0; r < 4; ++r) {
        float e0 = __expf(a0[r]); ls0[r] += e0;
        float e1 = __expf(a1[r]); ls1[r] += e1;
        Pw[(q * 4 + r) * 72 + st * 16 + m]        = (__bf16)e0;
        Pw[1152 + (q * 4 + r) * 72 + st * 16 + m] = (__bf16)e1;
      }
    }
    // ---- QK chunk B -> slice 1 ----
    if (hasB) {
#pragma unroll
      for (int st = 0; st < 4; ++st) {
        bf16x8 bK = *(const bf16x8*)(Kn + (sB + st * 16 + m) * ICH + q * 8);
        f32x4 a0 = __builtin_amdgcn_mfma_f32_16x16x32_bf16(aQ0, bK, zero, 0, 0, 0);
        f32x4 a1 = __builtin_amdgcn_mfma_f32_16x16x32_bf16(aQ1, bK, zero, 0, 0, 0);
#pragma unroll
        for (int r = 0; r < 4; ++r) {
          float e0 = __expf(a0[r]); ls0[r] += e0;
          float e1 = __expf(a1[r]); ls1[r] += e1;
          Pw[2304 + (q * 4 + r) * 72 + st * 16 + m] = (__bf16)e0;
          Pw[3456 + (q * 4 + r) * 72 + st * 16 + m] = (__bf16)e1;
        }
      }
    }
    // one wait for both slices (in-wave DS write->read ordering)
    asm volatile("s_waitcnt lgkmcnt(0)" ::: "memory");
    // ---- PV chunk A ----
#pragma unroll
    for (int kc = 0; kc < 2; ++kc) {
      bf16x8 aP0 = *(const bf16x8*)(Pw + m * 72 + kc * 32 + q * 8);
      bf16x8 aP1 = *(const bf16x8*)(Pw + 1152 + m * 72 + kc * 32 + q * 8);
#pragma unroll
      for (int ict = 0; ict < 2; ++ict) {
        bf16x8 bV = *(const bf16x8*)(Vn + (ict * 16 + m) * TV + sA + kc * 32 + q * 8);
        if (ict == 0) {
          o00 = __builtin_amdgcn_mfma_f32_16x16x32_bf16(aP0, bV, o00, 0, 0, 0);
          o10 = __builtin_amdgcn_mfma_f32_16x16x32_bf16(aP1, bV, o10, 0, 0, 0);
        } else {
          o01 = __builtin_amdgcn_mfma_f32_16x16x32_bf16(aP0, bV, o01, 0, 0, 0);
          o11 = __builtin_amdgcn_mfma_f32_16x16x32_bf16(aP1, bV, o11, 0, 0, 0);
        }
      }
    }
    // ---- PV chunk B ----
    if (hasB) {
#pragma unroll
      for (int kc = 0; kc < 2; ++kc) {
        bf16x8 aP0 = *(const bf16x8*)(Pw + 2304 + m * 72 + kc * 32 + q * 8);
        bf16x8 aP1 = *(const bf16x8*)(Pw + 3456 + m * 72 + kc * 32 + q * 8);
#pragma unroll
        for (int ict = 0; ict < 2; ++ict) {
          bf16x8 bV = *(const bf16x8*)(Vn + (ict * 16 + m) * TV + sB + kc * 32 + q * 8);
          if (ict == 0) {
            o00 = __builtin_amdgcn_mfma_f32_16x16x32_bf16(aP0, bV, o00, 0, 0, 0);
            o10 = __builtin_amdgcn_mfma_f32_16x16x32_bf16(aP1, bV, o10, 0, 0, 0);
          } else {
            o01 = __builtin_amdgcn_mfma_f32_16x16x32_bf16(aP0, bV, o01, 0, 0, 0);
            o11 = __builtin_amdgcn_mfma_f32_16x16x32_bf16(aP1, bV, o11, 0, 0, 0);
          }
        }
      }
    }
  }

  // row sums: reduce over the 16 m-lanes (C-layout rows live on fixed q)
#pragma unroll
  for (int mask = 1; mask <= 8; mask <<= 1) {
#pragma unroll
    for (int r = 0; r < 4; ++r) {
      ls0[r] += __shfl_xor(ls0[r], mask, 64);
      ls1[r] += __shfl_xor(ls1[r], mask, 64);
    }
  }

  // ---- merge 4 wave-partials through LDS (alias Pbuf area as f32) ----
  __syncthreads();                           // all waves done with Pbuf
  float* mf = (float*)lds;                   // 9216 f32 capacity
  float* mp = mf + (w * 64 + lane) * 24;     // 6144 f32 used
#pragma unroll
  for (int r = 0; r < 4; ++r) {
    mp[r]      = o00[r]; mp[4 + r]  = o01[r];
    mp[8 + r]  = o10[r]; mp[12 + r] = o11[r];
    mp[16 + r] = ls0[r]; mp[20 + r] = ls1[r];
  }
  __syncthreads();
  if (w == 0) {
#pragma unroll
    for (int ww = 1; ww < 4; ++ww) {
      const float* sp = mf + (ww * 64 + lane) * 24;
#pragma unroll
      for (int r = 0; r < 4; ++r) {
        o00[r] += sp[r];      o01[r] += sp[4 + r];
        o10[r] += sp[8 + r];  o11[r] += sp[12 + r];
        ls0[r] += sp[16 + r]; ls1[r] += sp[20 + r];
      }
    }
#pragma unroll
    for (int r = 0; r < 4; ++r) {
      float i0 = 1.f / ls0[r], i1 = 1.f / ls1[r];
      int pb0 = (n * TV + row0 + q * 4 + r) * ICH;
      int pb1 = pb0 + 16 * ICH;
      P[pb0 + m]      = o00[r] * i0;
      P[pb0 + 16 + m] = o01[r] * i0;
      P[pb1 + m]      = o10[r] * i1;
      P[pb1 + 16 + m] = o11[r] * i1;
    }
  }
}

// ---------------------------------------------------------------------------
// K4: trans-conv recompute + BN partial sums. Grid 800 = cg(8 ch)*100 + tb.
// PS2[800][16] = {sum_y[8], sum_y2[8]}.
// ---------------------------------------------------------------------------
__global__ __launch_bounds__(256) void stats_kernel(
    const float* __restrict__ P, const float* __restrict__ Wt,
    const float* __restrict__ bt, float* __restrict__ PS2) {
  int cg = blockIdx.x / 100;
  int tb = blockIdx.x % 100;
  int tvIdx = tb * 256 + threadIdx.x;
  int n = tvIdx / TV, tv = tvIdx % TV;

  union { f32x4 v[8]; float f[32]; } p;
  const f32x4* pp = (const f32x4*)(P + ((size_t)(n * TV + tv)) * ICH);
#pragma unroll
  for (int u = 0; u < 8; ++u) p.v[u] = pp[u];

  __shared__ float red[2][4][8];
  int w = threadIdx.x >> 6, lane = threadIdx.x & 63;
#pragma unroll
  for (int j = 0; j < 8; ++j) {
    int c = cg * 8 + j;
    float y = bt[c];
#pragma unroll
    for (int i = 0; i < ICH; ++i) y = fmaf(Wt[c * ICH + i], p.f[i], y);
    float y2 = y * y;
#pragma unroll
    for (int off = 32; off >= 1; off >>= 1) {
      y  += __shfl_xor(y,  off, 64);
      y2 += __shfl_xor(y2, off, 64);
    }
    if (lane == 0) { red[0][w][j] = y; red[1][w][j] = y2; }
  }
  __syncthreads();
  if (threadIdx.x < 16) {
    int which = threadIdx.x >> 3, j = threadIdx.x & 7;
    float s = red[which][0][j] + red[which][1][j] +
              red[which][2][j] + red[which][3][j];
    PS2[blockIdx.x * 16 + which * 8 + j] = s;
  }
}

// ---------------------------------------------------------------------------
// K5: finalize BN stats -> SS, plus ChannelGate MLP -> GATE.
// 1 block, 128 threads. AVG lives in d_out (overwritten later by apply).
// ---------------------------------------------------------------------------
__global__ __launch_bounds__(128) void finalize_stats(
    const float* __restrict__ PS2, const float* __restrict__ gamma,
    const float* __restrict__ beta, const float* __restrict__ AVG,
    const float* __restrict__ W1, const float* __restrict__ b1,
    const float* __restrict__ W2, const float* __restrict__ b2,
    float* __restrict__ SS, float* __restrict__ GATE) {
  int t = threadIdx.x;
  __shared__ float sh[NB][4];
  if (t < 64) {
    int c = t, cg = c >> 3, j = c & 7;
    float s = 0.f, ss = 0.f;
    for (int b = 0; b < 100; ++b) {
      int base = (cg * 100 + b) * 16;
      s  += PS2[base + j];
      ss += PS2[base + 8 + j];
    }
    float mean = s * (1.f / (float)NTV);
    float var  = ss * (1.f / (float)NTV) - mean * mean;
    float scale = rsqrtf(var + 1e-5f) * gamma[c];
    SS[c] = scale;
    SS[64 + c] = beta[c] - mean * scale;
    int n = t >> 2, jj = t & 3;
    float h = b1[jj];
    for (int c2 = 0; c2 < CC; ++c2)
      h = fmaf(W1[jj * CC + c2], AVG[n * CC + c2], h);
    sh[n][jj] = fmaxf(h, 0.f);
  }
  __syncthreads();
#pragma unroll
  for (int u = 0; u < 8; ++u) {
    int idx = t * 8 + u;
    int n = idx >> 6, c = idx & 63;
    float g = b2[c];
#pragma unroll
    for (int jj = 0; jj < 4; ++jj) g = fmaf(W2[c * 4 + jj], sh[n][jj], g);
    GATE[idx] = 1.f / (1.f + __expf(-g));
  }
}

// ---------------------------------------------------------------------------
// K6: recompute y for 8 channels, apply BN + gate + residual. Grid 800.
// ---------------------------------------------------------------------------
__global__ __launch_bounds__(256) void apply_kernel(
    const float* __restrict__ P, const float* __restrict__ Wt,
    const float* __restrict__ bt, const float* __restrict__ SS,
    const float* __restrict__ gate, const float* __restrict__ x,
    float* __restrict__ out) {
  int cg = blockIdx.x / 100;
  int tb = blockIdx.x % 100;
  int tvIdx = tb * 256 + threadIdx.x;
  int n = tvIdx / TV, tv = tvIdx % TV;

  union { f32x4 v[8]; float f[32]; } p;
  const f32x4* pp = (const f32x4*)(P + ((size_t)(n * TV + tv)) * ICH);
#pragma unroll
  for (int u = 0; u < 8; ++u) p.v[u] = pp[u];

#pragma unroll
  for (int j = 0; j < 8; ++j) {
    int c = cg * 8 + j;
    float y = bt[c];
#pragma unroll
    for (int i = 0; i < ICH; ++i) y = fmaf(Wt[c * ICH + i], p.f[i], y);
    size_t idx = ((size_t)(n * CC + c)) * TV + tv;
    out[idx] = gate[n * CC + c] * fmaf(y, SS[c], SS[64 + c]) + x[idx];
  }
}

// ---------------------------------------------------------------------------
extern "C" void kernel_launch(void* const* d_in, const int* in_sizes, int n_in,
                              void* d_out, int out_size, void* d_ws, size_t ws_size,
                              hipStream_t stream) {
  const float* x     = (const float*)d_in[0];
  const float* Wv    = (const float*)d_in[1];
  const float* bv    = (const float*)d_in[2];
  const float* Wk    = (const float*)d_in[3];
  const float* bk    = (const float*)d_in[4];
  const float* Wq    = (const float*)d_in[5];
  const float* bq    = (const float*)d_in[6];
  const float* Wt    = (const float*)d_in[7];
  const float* bt    = (const float*)d_in[8];
  const float* gamma = (const float*)d_in[9];
  const float* beta  = (const float*)d_in[10];
  const float* W1    = (const float*)d_in[11];
  const float* b1    = (const float*)d_in[12];
  const float* W2    = (const float*)d_in[13];
  const float* b2    = (const float*)d_in[14];
  float* out = (float*)d_out;
  char* ws = (char*)d_ws;

  // workspace layout (bytes) — total ~8.3 MB (< proven available)
  const size_t E = 819200;                    // N*TV*ICH elements
  __bf16* Qb  = (__bf16*)(ws);                // 2E bytes
  __bf16* Kb  = (__bf16*)(ws + 2*E);          // 2E bytes
  __bf16* VTb = (__bf16*)(ws + 4*E);          // 2E bytes
  float*  P   = (float*) (ws + 6*E);          // 4E bytes
  float*  PS2 = (float*) (ws + 10*E);         // 51200 B
  float*  SS  = (float*) (ws + 10*E + 51200); // 512 B
  float*  GATE= (float*) (ws + 10*E + 51712); // 4096 B
  float*  AVG = out;   // scratch: fully overwritten by apply_kernel

  proj_gate_kernel<<<464, 256, 0, stream>>>(x, Wv, bv, Wk, bk, Wq, bq,
                                            Qb, Kb, VTb, AVG);
  attn_kernel<<<NB * 50, 256, 0, stream>>>(Qb, Kb, VTb, P);
  stats_kernel<<<800, 256, 0, stream>>>(P, Wt, bt, PS2);
  finalize_stats<<<1, 128, 0, stream>>>(PS2, gamma, beta, AVG,
                                        W1, b1, W2, b2, SS, GATE);
  apply_kernel<<<800, 256, 0, stream>>>(P, Wt, bt, SS, GATE, x, out);
}

// Round 8
// 153.576 us; speedup vs baseline: 1.2972x; 1.0249x over previous
//
#include <hip/hip_runtime.h>
#include <hip/hip_bf16.h>
#include <math.h>

// Problem constants
#define NB   16      // batch
#define CC   64      // channels
#define ICH  32      // inter channels
#define TV   1600    // T*V = 64*25
#define NTV  (NB*TV) // 25600

typedef __bf16 bf16x8 __attribute__((ext_vector_type(8)));
typedef float  f32x4  __attribute__((ext_vector_type(4)));

// ---------------------------------------------------------------------------
// K1: 1x1 conv projections, p-split (12-way: 3 proj x 4 o-groups) for high
// TLP (4.7 waves/SIMD; the fused variant at 1.56 waves/SIMD was 14us slower).
// Blocks 0..1199: proj. 1200..1263: ChannelGate avg. 1264: zero GS.
//  Qb = k_x [N,TV,32]   Kb = q_x [N,TV,32]   VTb = v_x^T [N,32,TV]
// ---------------------------------------------------------------------------
__global__ __launch_bounds__(256) void proj_gate_kernel(
    const float* __restrict__ x,
    const float* __restrict__ Wv, const float* __restrict__ bv,
    const float* __restrict__ Wk, const float* __restrict__ bk,
    const float* __restrict__ Wq, const float* __restrict__ bq,
    __bf16* __restrict__ Qb, __bf16* __restrict__ Kb,
    __bf16* __restrict__ VTb, float* __restrict__ AVG,
    float* __restrict__ GS) {
  if (blockIdx.x == 1264) {               // zero the BN-stats accumulator
    if (threadIdx.x < 128) GS[threadIdx.x] = 0.f;
    return;
  }
  if (blockIdx.x >= 1200) {
    // ---- ChannelGate phase 1: per-(n, c) mean over TV ----
    int b = blockIdx.x - 1200;
    int n = b >> 2, cq = b & 3;
    int c16 = threadIdx.x >> 4, l = threadIdx.x & 15;
    int c = cq * 16 + c16;
    const float4* xp = (const float4*)(x + ((size_t)n * CC + c) * TV) + l;
    float s = 0.f;
#pragma unroll
    for (int i = 0; i < 25; ++i) {
      float4 v = xp[i * 16];
      s += v.x + v.y + v.z + v.w;
    }
#pragma unroll
    for (int off = 8; off >= 1; off >>= 1) s += __shfl_down(s, off, 16);
    if (l == 0) AVG[n * CC + c] = s * (1.0f / (float)TV);
    return;
  }

  int tile = blockIdx.x / 12;
  int sub  = blockIdx.x % 12;             // p*4 + og
  int p = sub >> 2, og = sub & 3;
  int ob = og * 8;
  int tvIdx = tile * 256 + threadIdx.x;   // 0..25599
  int n = tvIdx / TV, tv = tvIdx % TV;

  const float* W; const float* B;
  if (p == 0)      { W = Wv; B = bv; }
  else if (p == 1) { W = Wk; B = bk; }
  else             { W = Wq; B = bq; }

  float acc[8];
#pragma unroll
  for (int j = 0; j < 8; ++j) acc[j] = B[ob + j];

  const float* xp = x + (size_t)n * CC * TV + tv;
#pragma unroll 16
  for (int c = 0; c < CC; ++c) {
    float xc = xp[c * TV];
#pragma unroll
    for (int j = 0; j < 8; ++j)
      acc[j] = fmaf(W[(ob + j) * CC + c], xc, acc[j]);
  }

  if (p == 0) {                           // v_x -> transposed
#pragma unroll
    for (int j = 0; j < 8; ++j)
      VTb[(n * ICH + ob + j) * TV + tv] = (__bf16)acc[j];
  } else {
    bf16x8 t;
#pragma unroll
    for (int j = 0; j < 8; ++j) t[j] = (__bf16)acc[j];
    int base = (n * TV + tv) * ICH + ob;
    if (p == 1) *(bf16x8*)(Qb + base) = t;   // k_x -> attention rows
    else        *(bf16x8*)(Kb + base) = t;   // q_x -> attention cols
  }
}

// ---------------------------------------------------------------------------
// K2: MFMA flash attention (bf16, 2-chunk pipelined, 2 m-tiles/wave, XCD
// swizzle) + FUSED BN-STATS EPILOGUE: the block's normalized 32x32 P tile is
// parked in LDS; all 256 threads compute y = Wt*p + bt for 64 channels and
// atomicAdd per-channel {sum_y, sum_y2} partials into GS[128].
// P stored bf16. Grid = NB*50 = 800.
// ---------------------------------------------------------------------------
__global__ __launch_bounds__(256) void attn_kernel(
    const __bf16* __restrict__ Qb, const __bf16* __restrict__ Kb,
    const __bf16* __restrict__ VTb, __bf16* __restrict__ P,
    const float* __restrict__ Wt, const float* __restrict__ bt,
    float* __restrict__ GS) {
  // per wave: 2 slices x 2 tiles x (16 rows x 72) bf16 = 9216 B
  __shared__ __bf16 lds[4 * 4608];           // 36864 B total
  int b = blockIdx.x;
  int r8 = b & 7, qq = b >> 3;               // qq in [0,100)
  int n = r8 * 2 + (qq >= 50 ? 1 : 0);
  int rowTile = (qq >= 50) ? qq - 50 : qq;
  int row0 = rowTile * 32;

  int w = threadIdx.x >> 6;
  int lane = threadIdx.x & 63;
  int m = lane & 15, q = lane >> 4;

  __bf16* Pw = lds + w * 4608;               // [slice][tile][16][72]

  const __bf16* Qn = Qb  + (size_t)n * TV * ICH;
  const __bf16* Kn = Kb  + (size_t)n * TV * ICH;
  const __bf16* Vn = VTb + (size_t)n * ICH * TV;

  bf16x8 aQ0 = *(const bf16x8*)(Qn + (row0 + m) * ICH + q * 8);
  bf16x8 aQ1 = *(const bf16x8*)(Qn + (row0 + 16 + m) * ICH + q * 8);

  f32x4 o00 = {0.f,0.f,0.f,0.f}, o01 = {0.f,0.f,0.f,0.f};
  f32x4 o10 = {0.f,0.f,0.f,0.f}, o11 = {0.f,0.f,0.f,0.f};
  f32x4 ls0 = {0.f,0.f,0.f,0.f}, ls1 = {0.f,0.f,0.f,0.f};
  const f32x4 zero = {0.f,0.f,0.f,0.f};

  int nch = (w == 3) ? 7 : 6;                // wave w: chunks {4j + (3-w)}

  for (int jj = 0; jj < nch; jj += 2) {
    int sA = (4 * jj + (3 - w)) * 64;
    bool hasB = (jj + 1) < nch;
    int sB = hasB ? (4 * (jj + 1) + (3 - w)) * 64 : sA;

    // ---- QK chunk A -> slice 0 ----
#pragma unroll
    for (int st = 0; st < 4; ++st) {
      bf16x8 bK = *(const bf16x8*)(Kn + (sA + st * 16 + m) * ICH + q * 8);
      f32x4 a0 = __builtin_amdgcn_mfma_f32_16x16x32_bf16(aQ0, bK, zero, 0, 0, 0);
      f32x4 a1 = __builtin_amdgcn_mfma_f32_16x16x32_bf16(aQ1, bK, zero, 0, 0, 0);
#pragma unroll
      for (int r = 0; r < 4; ++r) {
        float e0 = __expf(a0[r]); ls0[r] += e0;
        float e1 = __expf(a1[r]); ls1[r] += e1;
        Pw[(q * 4 + r) * 72 + st * 16 + m]        = (__bf16)e0;
        Pw[1152 + (q * 4 + r) * 72 + st * 16 + m] = (__bf16)e1;
      }
    }
    // ---- QK chunk B -> slice 1 ----
    if (hasB) {
#pragma unroll
      for (int st = 0; st < 4; ++st) {
        bf16x8 bK = *(const bf16x8*)(Kn + (sB + st * 16 + m) * ICH + q * 8);
        f32x4 a0 = __builtin_amdgcn_mfma_f32_16x16x32_bf16(aQ0, bK, zero, 0, 0, 0);
        f32x4 a1 = __builtin_amdgcn_mfma_f32_16x16x32_bf16(aQ1, bK, zero, 0, 0, 0);
#pragma unroll
        for (int r = 0; r < 4; ++r) {
          float e0 = __expf(a0[r]); ls0[r] += e0;
          float e1 = __expf(a1[r]); ls1[r] += e1;
          Pw[2304 + (q * 4 + r) * 72 + st * 16 + m] = (__bf16)e0;
          Pw[3456 + (q * 4 + r) * 72 + st * 16 + m] = (__bf16)e1;
        }
      }
    }
    asm volatile("s_waitcnt lgkmcnt(0)" ::: "memory");
    // ---- PV chunk A ----
#pragma unroll
    for (int kc = 0; kc < 2; ++kc) {
      bf16x8 aP0 = *(const bf16x8*)(Pw + m * 72 + kc * 32 + q * 8);
      bf16x8 aP1 = *(const bf16x8*)(Pw + 1152 + m * 72 + kc * 32 + q * 8);
#pragma unroll
      for (int ict = 0; ict < 2; ++ict) {
        bf16x8 bV = *(const bf16x8*)(Vn + (ict * 16 + m) * TV + sA + kc * 32 + q * 8);
        if (ict == 0) {
          o00 = __builtin_amdgcn_mfma_f32_16x16x32_bf16(aP0, bV, o00, 0, 0, 0);
          o10 = __builtin_amdgcn_mfma_f32_16x16x32_bf16(aP1, bV, o10, 0, 0, 0);
        } else {
          o01 = __builtin_amdgcn_mfma_f32_16x16x32_bf16(aP0, bV, o01, 0, 0, 0);
          o11 = __builtin_amdgcn_mfma_f32_16x16x32_bf16(aP1, bV, o11, 0, 0, 0);
        }
      }
    }
    // ---- PV chunk B ----
    if (hasB) {
#pragma unroll
      for (int kc = 0; kc < 2; ++kc) {
        bf16x8 aP0 = *(const bf16x8*)(Pw + 2304 + m * 72 + kc * 32 + q * 8);
        bf16x8 aP1 = *(const bf16x8*)(Pw + 3456 + m * 72 + kc * 32 + q * 8);
#pragma unroll
        for (int ict = 0; ict < 2; ++ict) {
          bf16x8 bV = *(const bf16x8*)(Vn + (ict * 16 + m) * TV + sB + kc * 32 + q * 8);
          if (ict == 0) {
            o00 = __builtin_amdgcn_mfma_f32_16x16x32_bf16(aP0, bV, o00, 0, 0, 0);
            o10 = __builtin_amdgcn_mfma_f32_16x16x32_bf16(aP1, bV, o10, 0, 0, 0);
          } else {
            o01 = __builtin_amdgcn_mfma_f32_16x16x32_bf16(aP0, bV, o01, 0, 0, 0);
            o11 = __builtin_amdgcn_mfma_f32_16x16x32_bf16(aP1, bV, o11, 0, 0, 0);
          }
        }
      }
    }
  }

  // row sums: reduce over the 16 m-lanes (C-layout rows live on fixed q)
#pragma unroll
  for (int mask = 1; mask <= 8; mask <<= 1) {
#pragma unroll
    for (int r = 0; r < 4; ++r) {
      ls0[r] += __shfl_xor(ls0[r], mask, 64);
      ls1[r] += __shfl_xor(ls1[r], mask, 64);
    }
  }

  // ---- merge 4 wave-partials through LDS (alias Pbuf area as f32) ----
  float* mf = (float*)lds;                   // 9216 f32 capacity
  float* Pl = mf + 6144;                     // [32][33] normalized P tile
  float* red = mf + 7424;                    // [4 rg][{y,y2}][64]

  __syncthreads();                           // all waves done with Pbuf
  float* mp = mf + (w * 64 + lane) * 24;     // 6144 f32 used
#pragma unroll
  for (int r = 0; r < 4; ++r) {
    mp[r]      = o00[r]; mp[4 + r]  = o01[r];
    mp[8 + r]  = o10[r]; mp[12 + r] = o11[r];
    mp[16 + r] = ls0[r]; mp[20 + r] = ls1[r];
  }
  __syncthreads();
  if (w == 0) {
#pragma unroll
    for (int ww = 1; ww < 4; ++ww) {
      const float* sp = mf + (ww * 64 + lane) * 24;
#pragma unroll
      for (int r = 0; r < 4; ++r) {
        o00[r] += sp[r];      o01[r] += sp[4 + r];
        o10[r] += sp[8 + r];  o11[r] += sp[12 + r];
        ls0[r] += sp[16 + r]; ls1[r] += sp[20 + r];
      }
    }
#pragma unroll
    for (int r = 0; r < 4; ++r) {
      float i0 = 1.f / ls0[r], i1 = 1.f / ls1[r];
      float p00 = o00[r] * i0, p01 = o01[r] * i0;
      float p10 = o10[r] * i1, p11 = o11[r] * i1;
      int pb0 = (n * TV + row0 + q * 4 + r) * ICH;
      int pb1 = pb0 + 16 * ICH;
      P[pb0 + m]      = (__bf16)p00;
      P[pb0 + 16 + m] = (__bf16)p01;
      P[pb1 + m]      = (__bf16)p10;
      P[pb1 + 16 + m] = (__bf16)p11;
      Pl[(q * 4 + r) * 33 + m]           = p00;
      Pl[(q * 4 + r) * 33 + 16 + m]      = p01;
      Pl[(16 + q * 4 + r) * 33 + m]      = p10;
      Pl[(16 + q * 4 + r) * 33 + 16 + m] = p11;
    }
  }
  __syncthreads();

  // ---- fused BN stats: thread (c = t&63, rg = w) does 8 rows x 64ch dot ----
  int c = threadIdx.x & 63;
  float wr[ICH];
#pragma unroll
  for (int i = 0; i < ICH; ++i) wr[i] = Wt[c * ICH + i];
  float bc = bt[c];
  float sy = 0.f, sy2 = 0.f;
#pragma unroll
  for (int rr = 0; rr < 8; ++rr) {
    const float* pr = Pl + (w * 8 + rr) * 33;   // same addr across wave: bcast
    float y = bc;
#pragma unroll
    for (int i = 0; i < ICH; ++i) y = fmaf(wr[i], pr[i], y);
    sy += y; sy2 += y * y;
  }
  red[w * 128 + c]      = sy;
  red[w * 128 + 64 + c] = sy2;
  __syncthreads();
  if (threadIdx.x < 128) {
    int which = threadIdx.x >> 6, cc = threadIdx.x & 63;
    float s = red[which * 64 + cc]       + red[128 + which * 64 + cc] +
              red[256 + which * 64 + cc] + red[384 + which * 64 + cc];
    atomicAdd(GS + which * 64 + cc, s);
  }
}

// ---------------------------------------------------------------------------
// K3: finalize BN stats (from GS) -> SS, plus ChannelGate MLP -> GATE.
// 1 block, 128 threads. AVG lives in d_out (overwritten later by apply).
// ---------------------------------------------------------------------------
__global__ __launch_bounds__(128) void finalize_stats(
    const float* __restrict__ GS, const float* __restrict__ gamma,
    const float* __restrict__ beta, const float* __restrict__ AVG,
    const float* __restrict__ W1, const float* __restrict__ b1,
    const float* __restrict__ W2, const float* __restrict__ b2,
    float* __restrict__ SS, float* __restrict__ GATE) {
  int t = threadIdx.x;
  __shared__ float sh[NB][4];
  if (t < 64) {
    int c = t;
    float mean = GS[c] * (1.f / (float)NTV);
    float var  = GS[64 + c] * (1.f / (float)NTV) - mean * mean;
    float scale = rsqrtf(var + 1e-5f) * gamma[c];
    SS[c] = scale;
    SS[64 + c] = beta[c] - mean * scale;
    int n = t >> 2, jj = t & 3;
    float h = b1[jj];
    for (int c2 = 0; c2 < CC; ++c2)
      h = fmaf(W1[jj * CC + c2], AVG[n * CC + c2], h);
    sh[n][jj] = fmaxf(h, 0.f);
  }
  __syncthreads();
#pragma unroll
  for (int u = 0; u < 8; ++u) {
    int idx = t * 8 + u;
    int n = idx >> 6, c = idx & 63;
    float g = b2[c];
#pragma unroll
    for (int jj = 0; jj < 4; ++jj) g = fmaf(W2[c * 4 + jj], sh[n][jj], g);
    GATE[idx] = 1.f / (1.f + __expf(-g));
  }
}

// ---------------------------------------------------------------------------
// K4: recompute y for 8 channels from bf16 P, apply BN + gate + residual.
// Grid 800 = cg(8 ch)*100 + tb.
// ---------------------------------------------------------------------------
__global__ __launch_bounds__(256) void apply_kernel(
    const __bf16* __restrict__ P, const float* __restrict__ Wt,
    const float* __restrict__ bt, const float* __restrict__ SS,
    const float* __restrict__ gate, const float* __restrict__ x,
    float* __restrict__ out) {
  int cg = blockIdx.x / 100;
  int tb = blockIdx.x % 100;
  int tvIdx = tb * 256 + threadIdx.x;
  int n = tvIdx / TV, tv = tvIdx % TV;

  float f[ICH];
  const bf16x8* pp = (const bf16x8*)(P + ((size_t)(n * TV + tv)) * ICH);
#pragma unroll
  for (int u = 0; u < 4; ++u) {
    bf16x8 v = pp[u];
#pragma unroll
    for (int j = 0; j < 8; ++j) f[u * 8 + j] = (float)v[j];
  }

#pragma unroll
  for (int j = 0; j < 8; ++j) {
    int c = cg * 8 + j;
    float y = bt[c];
#pragma unroll
    for (int i = 0; i < ICH; ++i) y = fmaf(Wt[c * ICH + i], f[i], y);
    size_t idx = ((size_t)(n * CC + c)) * TV + tv;
    out[idx] = gate[n * CC + c] * fmaf(y, SS[c], SS[64 + c]) + x[idx];
  }
}

// ---------------------------------------------------------------------------
extern "C" void kernel_launch(void* const* d_in, const int* in_sizes, int n_in,
                              void* d_out, int out_size, void* d_ws, size_t ws_size,
                              hipStream_t stream) {
  const float* x     = (const float*)d_in[0];
  const float* Wv    = (const float*)d_in[1];
  const float* bv    = (const float*)d_in[2];
  const float* Wk    = (const float*)d_in[3];
  const float* bk    = (const float*)d_in[4];
  const float* Wq    = (const float*)d_in[5];
  const float* bq    = (const float*)d_in[6];
  const float* Wt    = (const float*)d_in[7];
  const float* bt    = (const float*)d_in[8];
  const float* gamma = (const float*)d_in[9];
  const float* beta  = (const float*)d_in[10];
  const float* W1    = (const float*)d_in[11];
  const float* b1    = (const float*)d_in[12];
  const float* W2    = (const float*)d_in[13];
  const float* b2    = (const float*)d_in[14];
  float* out = (float*)d_out;
  char* ws = (char*)d_ws;

  // workspace layout (bytes) — total ~6.6 MB
  const size_t E = 819200;                    // N*TV*ICH elements
  __bf16* Qb  = (__bf16*)(ws);                // 2E bytes
  __bf16* Kb  = (__bf16*)(ws + 2*E);          // 2E bytes
  __bf16* VTb = (__bf16*)(ws + 4*E);          // 2E bytes
  __bf16* Pb  = (__bf16*)(ws + 6*E);          // 2E bytes
  float*  GS  = (float*) (ws + 8*E);          // 512 B {sum_y, sum_y2}
  float*  SS  = (float*) (ws + 8*E + 512);    // 512 B
  float*  GATE= (float*) (ws + 8*E + 1024);   // 4096 B
  float*  AVG = out;   // scratch: fully overwritten by apply_kernel

  proj_gate_kernel<<<1265, 256, 0, stream>>>(x, Wv, bv, Wk, bk, Wq, bq,
                                             Qb, Kb, VTb, AVG, GS);
  attn_kernel<<<NB * 50, 256, 0, stream>>>(Qb, Kb, VTb, Pb, Wt, bt, GS);
  finalize_stats<<<1, 128, 0, stream>>>(GS, gamma, beta, AVG,
                                        W1, b1, W2, b2, SS, GATE);
  apply_kernel<<<800, 256, 0, stream>>>(Pb, Wt, bt, SS, GATE, x, out);
}

// Round 9
// 148.773 us; speedup vs baseline: 1.3391x; 1.0323x over previous
//
#include <hip/hip_runtime.h>
#include <hip/hip_bf16.h>
#include <math.h>

// Problem constants
#define NB   16      // batch
#define CC   64      // channels
#define ICH  32      // inter channels
#define TV   1600    // T*V = 64*25
#define NTV  (NB*TV) // 25600

typedef __bf16 bf16x8 __attribute__((ext_vector_type(8)));
typedef float  f32x4  __attribute__((ext_vector_type(4)));

// ---------------------------------------------------------------------------
// K1: 1x1 conv projections, p-split (12-way: 3 proj x 4 o-groups) for high
// TLP. Blocks 0..1199: proj. 1200..1263: ChannelGate avg.
//  Qb = k_x [N,TV,32]   Kb = q_x [N,TV,32]   VTb = v_x^T [N,32,TV]
// ---------------------------------------------------------------------------
__global__ __launch_bounds__(256) void proj_gate_kernel(
    const float* __restrict__ x,
    const float* __restrict__ Wv, const float* __restrict__ bv,
    const float* __restrict__ Wk, const float* __restrict__ bk,
    const float* __restrict__ Wq, const float* __restrict__ bq,
    __bf16* __restrict__ Qb, __bf16* __restrict__ Kb,
    __bf16* __restrict__ VTb, float* __restrict__ AVG) {
  if (blockIdx.x >= 1200) {
    // ---- ChannelGate phase 1: per-(n, c) mean over TV ----
    int b = blockIdx.x - 1200;
    int n = b >> 2, cq = b & 3;
    int c16 = threadIdx.x >> 4, l = threadIdx.x & 15;
    int c = cq * 16 + c16;
    const float4* xp = (const float4*)(x + ((size_t)n * CC + c) * TV) + l;
    float s = 0.f;
#pragma unroll
    for (int i = 0; i < 25; ++i) {
      float4 v = xp[i * 16];
      s += v.x + v.y + v.z + v.w;
    }
#pragma unroll
    for (int off = 8; off >= 1; off >>= 1) s += __shfl_down(s, off, 16);
    if (l == 0) AVG[n * CC + c] = s * (1.0f / (float)TV);
    return;
  }

  int tile = blockIdx.x / 12;
  int sub  = blockIdx.x % 12;             // p*4 + og
  int p = sub >> 2, og = sub & 3;
  int ob = og * 8;
  int tvIdx = tile * 256 + threadIdx.x;   // 0..25599
  int n = tvIdx / TV, tv = tvIdx % TV;

  const float* W; const float* B;
  if (p == 0)      { W = Wv; B = bv; }
  else if (p == 1) { W = Wk; B = bk; }
  else             { W = Wq; B = bq; }

  float acc[8];
#pragma unroll
  for (int j = 0; j < 8; ++j) acc[j] = B[ob + j];

  const float* xp = x + (size_t)n * CC * TV + tv;
#pragma unroll 16
  for (int c = 0; c < CC; ++c) {
    float xc = xp[c * TV];
#pragma unroll
    for (int j = 0; j < 8; ++j)
      acc[j] = fmaf(W[(ob + j) * CC + c], xc, acc[j]);
  }

  if (p == 0) {                           // v_x -> transposed
#pragma unroll
    for (int j = 0; j < 8; ++j)
      VTb[(n * ICH + ob + j) * TV + tv] = (__bf16)acc[j];
  } else {
    bf16x8 t;
#pragma unroll
    for (int j = 0; j < 8; ++j) t[j] = (__bf16)acc[j];
    int base = (n * TV + tv) * ICH + ob;
    if (p == 1) *(bf16x8*)(Qb + base) = t;   // k_x -> attention rows
    else        *(bf16x8*)(Kb + base) = t;   // q_x -> attention cols
  }
}

// ---------------------------------------------------------------------------
// K2: MFMA flash attention (bf16, 2-chunk pipelined, 2 m-tiles/wave, XCD
// swizzle) + fused BN-stats epilogue. Per-block partials stored to a PRIVATE
// GSP[block][128] slot (no atomics -- R8's 102k same-address atomicAdds were
// a ~15-25us serialization tail). Pl row stride 36 -> 16B-aligned b128
// broadcast reads. P stored bf16. Grid = NB*50 = 800.
// ---------------------------------------------------------------------------
__global__ __launch_bounds__(256) void attn_kernel(
    const __bf16* __restrict__ Qb, const __bf16* __restrict__ Kb,
    const __bf16* __restrict__ VTb, __bf16* __restrict__ P,
    const float* __restrict__ Wt, const float* __restrict__ bt,
    float* __restrict__ GSP) {
  // per wave: 2 slices x 2 tiles x (16 rows x 72) bf16 = 9216 B
  __shared__ __bf16 lds[4 * 4608];           // 36864 B total
  int b = blockIdx.x;
  int r8 = b & 7, qq = b >> 3;               // qq in [0,100)
  int n = r8 * 2 + (qq >= 50 ? 1 : 0);
  int rowTile = (qq >= 50) ? qq - 50 : qq;
  int row0 = rowTile * 32;

  int w = threadIdx.x >> 6;
  int lane = threadIdx.x & 63;
  int m = lane & 15, q = lane >> 4;

  __bf16* Pw = lds + w * 4608;               // [slice][tile][16][72]

  const __bf16* Qn = Qb  + (size_t)n * TV * ICH;
  const __bf16* Kn = Kb  + (size_t)n * TV * ICH;
  const __bf16* Vn = VTb + (size_t)n * ICH * TV;

  bf16x8 aQ0 = *(const bf16x8*)(Qn + (row0 + m) * ICH + q * 8);
  bf16x8 aQ1 = *(const bf16x8*)(Qn + (row0 + 16 + m) * ICH + q * 8);

  f32x4 o00 = {0.f,0.f,0.f,0.f}, o01 = {0.f,0.f,0.f,0.f};
  f32x4 o10 = {0.f,0.f,0.f,0.f}, o11 = {0.f,0.f,0.f,0.f};
  f32x4 ls0 = {0.f,0.f,0.f,0.f}, ls1 = {0.f,0.f,0.f,0.f};
  const f32x4 zero = {0.f,0.f,0.f,0.f};

  int nch = (w == 3) ? 7 : 6;                // wave w: chunks {4j + (3-w)}

  for (int jj = 0; jj < nch; jj += 2) {
    int sA = (4 * jj + (3 - w)) * 64;
    bool hasB = (jj + 1) < nch;
    int sB = hasB ? (4 * (jj + 1) + (3 - w)) * 64 : sA;

    // ---- QK chunk A -> slice 0 ----
#pragma unroll
    for (int st = 0; st < 4; ++st) {
      bf16x8 bK = *(const bf16x8*)(Kn + (sA + st * 16 + m) * ICH + q * 8);
      f32x4 a0 = __builtin_amdgcn_mfma_f32_16x16x32_bf16(aQ0, bK, zero, 0, 0, 0);
      f32x4 a1 = __builtin_amdgcn_mfma_f32_16x16x32_bf16(aQ1, bK, zero, 0, 0, 0);
#pragma unroll
      for (int r = 0; r < 4; ++r) {
        float e0 = __expf(a0[r]); ls0[r] += e0;
        float e1 = __expf(a1[r]); ls1[r] += e1;
        Pw[(q * 4 + r) * 72 + st * 16 + m]        = (__bf16)e0;
        Pw[1152 + (q * 4 + r) * 72 + st * 16 + m] = (__bf16)e1;
      }
    }
    // ---- QK chunk B -> slice 1 ----
    if (hasB) {
#pragma unroll
      for (int st = 0; st < 4; ++st) {
        bf16x8 bK = *(const bf16x8*)(Kn + (sB + st * 16 + m) * ICH + q * 8);
        f32x4 a0 = __builtin_amdgcn_mfma_f32_16x16x32_bf16(aQ0, bK, zero, 0, 0, 0);
        f32x4 a1 = __builtin_amdgcn_mfma_f32_16x16x32_bf16(aQ1, bK, zero, 0, 0, 0);
#pragma unroll
        for (int r = 0; r < 4; ++r) {
          float e0 = __expf(a0[r]); ls0[r] += e0;
          float e1 = __expf(a1[r]); ls1[r] += e1;
          Pw[2304 + (q * 4 + r) * 72 + st * 16 + m] = (__bf16)e0;
          Pw[3456 + (q * 4 + r) * 72 + st * 16 + m] = (__bf16)e1;
        }
      }
    }
    asm volatile("s_waitcnt lgkmcnt(0)" ::: "memory");
    // ---- PV chunk A ----
#pragma unroll
    for (int kc = 0; kc < 2; ++kc) {
      bf16x8 aP0 = *(const bf16x8*)(Pw + m * 72 + kc * 32 + q * 8);
      bf16x8 aP1 = *(const bf16x8*)(Pw + 1152 + m * 72 + kc * 32 + q * 8);
#pragma unroll
      for (int ict = 0; ict < 2; ++ict) {
        bf16x8 bV = *(const bf16x8*)(Vn + (ict * 16 + m) * TV + sA + kc * 32 + q * 8);
        if (ict == 0) {
          o00 = __builtin_amdgcn_mfma_f32_16x16x32_bf16(aP0, bV, o00, 0, 0, 0);
          o10 = __builtin_amdgcn_mfma_f32_16x16x32_bf16(aP1, bV, o10, 0, 0, 0);
        } else {
          o01 = __builtin_amdgcn_mfma_f32_16x16x32_bf16(aP0, bV, o01, 0, 0, 0);
          o11 = __builtin_amdgcn_mfma_f32_16x16x32_bf16(aP1, bV, o11, 0, 0, 0);
        }
      }
    }
    // ---- PV chunk B ----
    if (hasB) {
#pragma unroll
      for (int kc = 0; kc < 2; ++kc) {
        bf16x8 aP0 = *(const bf16x8*)(Pw + 2304 + m * 72 + kc * 32 + q * 8);
        bf16x8 aP1 = *(const bf16x8*)(Pw + 3456 + m * 72 + kc * 32 + q * 8);
#pragma unroll
        for (int ict = 0; ict < 2; ++ict) {
          bf16x8 bV = *(const bf16x8*)(Vn + (ict * 16 + m) * TV + sB + kc * 32 + q * 8);
          if (ict == 0) {
            o00 = __builtin_amdgcn_mfma_f32_16x16x32_bf16(aP0, bV, o00, 0, 0, 0);
            o10 = __builtin_amdgcn_mfma_f32_16x16x32_bf16(aP1, bV, o10, 0, 0, 0);
          } else {
            o01 = __builtin_amdgcn_mfma_f32_16x16x32_bf16(aP0, bV, o01, 0, 0, 0);
            o11 = __builtin_amdgcn_mfma_f32_16x16x32_bf16(aP1, bV, o11, 0, 0, 0);
          }
        }
      }
    }
  }

  // row sums: reduce over the 16 m-lanes (C-layout rows live on fixed q)
#pragma unroll
  for (int mask = 1; mask <= 8; mask <<= 1) {
#pragma unroll
    for (int r = 0; r < 4; ++r) {
      ls0[r] += __shfl_xor(ls0[r], mask, 64);
      ls1[r] += __shfl_xor(ls1[r], mask, 64);
    }
  }

  // ---- merge 4 wave-partials through LDS (alias Pbuf area as f32) ----
  float* mf = (float*)lds;                   // 9216 f32 capacity
  float* Pl = mf + 6144;                     // [32][36] normalized P tile
  float* red = mf + 7296;                    // [4 waves][128]

  __syncthreads();                           // all waves done with Pbuf
  float* mp = mf + (w * 64 + lane) * 24;     // 6144 f32 used
#pragma unroll
  for (int r = 0; r < 4; ++r) {
    mp[r]      = o00[r]; mp[4 + r]  = o01[r];
    mp[8 + r]  = o10[r]; mp[12 + r] = o11[r];
    mp[16 + r] = ls0[r]; mp[20 + r] = ls1[r];
  }
  __syncthreads();
  if (w == 0) {
#pragma unroll
    for (int ww = 1; ww < 4; ++ww) {
      const float* sp = mf + (ww * 64 + lane) * 24;
#pragma unroll
      for (int r = 0; r < 4; ++r) {
        o00[r] += sp[r];      o01[r] += sp[4 + r];
        o10[r] += sp[8 + r];  o11[r] += sp[12 + r];
        ls0[r] += sp[16 + r]; ls1[r] += sp[20 + r];
      }
    }
#pragma unroll
    for (int r = 0; r < 4; ++r) {
      float i0 = 1.f / ls0[r], i1 = 1.f / ls1[r];
      float p00 = o00[r] * i0, p01 = o01[r] * i0;
      float p10 = o10[r] * i1, p11 = o11[r] * i1;
      int pb0 = (n * TV + row0 + q * 4 + r) * ICH;
      int pb1 = pb0 + 16 * ICH;
      P[pb0 + m]      = (__bf16)p00;
      P[pb0 + 16 + m] = (__bf16)p01;
      P[pb1 + m]      = (__bf16)p10;
      P[pb1 + 16 + m] = (__bf16)p11;
      Pl[(q * 4 + r) * 36 + m]           = p00;
      Pl[(q * 4 + r) * 36 + 16 + m]      = p01;
      Pl[(16 + q * 4 + r) * 36 + m]      = p10;
      Pl[(16 + q * 4 + r) * 36 + 16 + m] = p11;
    }
  }
  __syncthreads();

  // ---- fused BN stats: thread (c = t&63, rg = w) does 8 rows x 64ch dot.
  // Pl reads are wave-uniform b128 broadcasts (stride 36 -> 16B-aligned).
  int c = threadIdx.x & 63;
  float wr[ICH];
#pragma unroll
  for (int i = 0; i < ICH; ++i) wr[i] = Wt[c * ICH + i];
  float bc = bt[c];
  float sy = 0.f, sy2 = 0.f;
#pragma unroll
  for (int rr = 0; rr < 8; ++rr) {
    const f32x4* pr = (const f32x4*)(Pl + (w * 8 + rr) * 36);
    float y = bc;
#pragma unroll
    for (int u = 0; u < 8; ++u) {
      f32x4 pv = pr[u];
#pragma unroll
      for (int k = 0; k < 4; ++k) y = fmaf(wr[u * 4 + k], pv[k], y);
    }
    sy += y; sy2 += y * y;
  }
  red[w * 128 + c]      = sy;
  red[w * 128 + 64 + c] = sy2;
  __syncthreads();
  if (threadIdx.x < 128) {
    int t = threadIdx.x;
    float s = red[t] + red[128 + t] + red[256 + t] + red[384 + t];
    GSP[(size_t)blockIdx.x * 128 + t] = s;   // private slot, no atomics
  }
}

// ---------------------------------------------------------------------------
// K3: sum GSP[800][128] -> BN scale/shift SS, plus ChannelGate MLP -> GATE.
// 1 block, 256 threads (2-way split over the 800 slots).
// AVG lives in d_out (overwritten later by apply).
// ---------------------------------------------------------------------------
__global__ __launch_bounds__(256) void finalize_stats(
    const float* __restrict__ GSP, const float* __restrict__ gamma,
    const float* __restrict__ beta, const float* __restrict__ AVG,
    const float* __restrict__ W1, const float* __restrict__ b1,
    const float* __restrict__ W2, const float* __restrict__ b2,
    float* __restrict__ SS, float* __restrict__ GATE) {
  int t = threadIdx.x;
  __shared__ float acc2[2][128];
  __shared__ float shs[128];
  __shared__ float sh[NB][4];
  {
    int c = t & 127, half = t >> 7;
    float s = 0.f;
    for (int b = half * 400; b < half * 400 + 400; ++b)
      s += GSP[(size_t)b * 128 + c];
    acc2[half][c] = s;
  }
  __syncthreads();
  if (t < 128) shs[t] = acc2[0][t] + acc2[1][t];
  __syncthreads();
  if (t < 64) {
    int c = t;
    float mean = shs[c] * (1.f / (float)NTV);
    float var  = shs[64 + c] * (1.f / (float)NTV) - mean * mean;
    float scale = rsqrtf(var + 1e-5f) * gamma[c];
    SS[c] = scale;
    SS[64 + c] = beta[c] - mean * scale;
    int n = t >> 2, jj = t & 3;
    float h = b1[jj];
    for (int c2 = 0; c2 < CC; ++c2)
      h = fmaf(W1[jj * CC + c2], AVG[n * CC + c2], h);
    sh[n][jj] = fmaxf(h, 0.f);
  }
  __syncthreads();
#pragma unroll
  for (int u = 0; u < 4; ++u) {
    int idx = t * 4 + u;
    int n = idx >> 6, c = idx & 63;
    float g = b2[c];
#pragma unroll
    for (int jj = 0; jj < 4; ++jj) g = fmaf(W2[c * 4 + jj], sh[n][jj], g);
    GATE[idx] = 1.f / (1.f + __expf(-g));
  }
}

// ---------------------------------------------------------------------------
// K4: recompute y for 8 channels from bf16 P, apply BN + gate + residual.
// Grid 800 = cg(8 ch)*100 + tb.
// ---------------------------------------------------------------------------
__global__ __launch_bounds__(256) void apply_kernel(
    const __bf16* __restrict__ P, const float* __restrict__ Wt,
    const float* __restrict__ bt, const float* __restrict__ SS,
    const float* __restrict__ gate, const float* __restrict__ x,
    float* __restrict__ out) {
  int cg = blockIdx.x / 100;
  int tb = blockIdx.x % 100;
  int tvIdx = tb * 256 + threadIdx.x;
  int n = tvIdx / TV, tv = tvIdx % TV;

  float f[ICH];
  const bf16x8* pp = (const bf16x8*)(P + ((size_t)(n * TV + tv)) * ICH);
#pragma unroll
  for (int u = 0; u < 4; ++u) {
    bf16x8 v = pp[u];
#pragma unroll
    for (int j = 0; j < 8; ++j) f[u * 8 + j] = (float)v[j];
  }

#pragma unroll
  for (int j = 0; j < 8; ++j) {
    int c = cg * 8 + j;
    float y = bt[c];
#pragma unroll
    for (int i = 0; i < ICH; ++i) y = fmaf(Wt[c * ICH + i], f[i], y);
    size_t idx = ((size_t)(n * CC + c)) * TV + tv;
    out[idx] = gate[n * CC + c] * fmaf(y, SS[c], SS[64 + c]) + x[idx];
  }
}

// ---------------------------------------------------------------------------
extern "C" void kernel_launch(void* const* d_in, const int* in_sizes, int n_in,
                              void* d_out, int out_size, void* d_ws, size_t ws_size,
                              hipStream_t stream) {
  const float* x     = (const float*)d_in[0];
  const float* Wv    = (const float*)d_in[1];
  const float* bv    = (const float*)d_in[2];
  const float* Wk    = (const float*)d_in[3];
  const float* bk    = (const float*)d_in[4];
  const float* Wq    = (const float*)d_in[5];
  const float* bq    = (const float*)d_in[6];
  const float* Wt    = (const float*)d_in[7];
  const float* bt    = (const float*)d_in[8];
  const float* gamma = (const float*)d_in[9];
  const float* beta  = (const float*)d_in[10];
  const float* W1    = (const float*)d_in[11];
  const float* b1    = (const float*)d_in[12];
  const float* W2    = (const float*)d_in[13];
  const float* b2    = (const float*)d_in[14];
  float* out = (float*)d_out;
  char* ws = (char*)d_ws;

  // workspace layout (bytes) — total ~7.0 MB
  const size_t E = 819200;                    // N*TV*ICH elements
  __bf16* Qb  = (__bf16*)(ws);                // 2E bytes
  __bf16* Kb  = (__bf16*)(ws + 2*E);          // 2E bytes
  __bf16* VTb = (__bf16*)(ws + 4*E);          // 2E bytes
  __bf16* Pb  = (__bf16*)(ws + 6*E);          // 2E bytes
  float*  GSP = (float*) (ws + 8*E);          // 409600 B per-block partials
  float*  SS  = (float*) (ws + 8*E + 409600); // 512 B
  float*  GATE= (float*) (ws + 8*E + 410112); // 4096 B
  float*  AVG = out;   // scratch: fully overwritten by apply_kernel

  proj_gate_kernel<<<1264, 256, 0, stream>>>(x, Wv, bv, Wk, bk, Wq, bq,
                                             Qb, Kb, VTb, AVG);
  attn_kernel<<<NB * 50, 256, 0, stream>>>(Qb, Kb, VTb, Pb, Wt, bt, GSP);
  finalize_stats<<<1, 256, 0, stream>>>(GSP, gamma, beta, AVG,
                                        W1, b1, W2, b2, SS, GATE);
  apply_kernel<<<800, 256, 0, stream>>>(Pb, Wt, bt, SS, GATE, x, out);
}

// Round 10
// 142.743 us; speedup vs baseline: 1.3956x; 1.0422x over previous
//
#include <hip/hip_runtime.h>
#include <hip/hip_bf16.h>
#include <math.h>

// Problem constants
#define NB   16      // batch
#define CC   64      // channels
#define ICH  32      // inter channels
#define TV   1600    // T*V = 64*25
#define NTV  (NB*TV) // 25600

typedef __bf16 bf16x8 __attribute__((ext_vector_type(8)));
typedef float  f32x4  __attribute__((ext_vector_type(4)));

// ---------------------------------------------------------------------------
// K1: 1x1 conv projections, p-split (12-way: 3 proj x 4 o-groups) for high
// TLP. Blocks 0..1199: proj. 1200..1263: ChannelGate avg.
//  Qb = k_x [N,TV,32]   Kb = q_x [N,TV,32]   VTb = v_x^T [N,32,TV]
// ---------------------------------------------------------------------------
__global__ __launch_bounds__(256) void proj_gate_kernel(
    const float* __restrict__ x,
    const float* __restrict__ Wv, const float* __restrict__ bv,
    const float* __restrict__ Wk, const float* __restrict__ bk,
    const float* __restrict__ Wq, const float* __restrict__ bq,
    __bf16* __restrict__ Qb, __bf16* __restrict__ Kb,
    __bf16* __restrict__ VTb, float* __restrict__ AVG) {
  if (blockIdx.x >= 1200) {
    // ---- ChannelGate phase 1: per-(n, c) mean over TV ----
    int b = blockIdx.x - 1200;
    int n = b >> 2, cq = b & 3;
    int c16 = threadIdx.x >> 4, l = threadIdx.x & 15;
    int c = cq * 16 + c16;
    const float4* xp = (const float4*)(x + ((size_t)n * CC + c) * TV) + l;
    float s = 0.f;
#pragma unroll
    for (int i = 0; i < 25; ++i) {
      float4 v = xp[i * 16];
      s += v.x + v.y + v.z + v.w;
    }
#pragma unroll
    for (int off = 8; off >= 1; off >>= 1) s += __shfl_down(s, off, 16);
    if (l == 0) AVG[n * CC + c] = s * (1.0f / (float)TV);
    return;
  }

  int tile = blockIdx.x / 12;
  int sub  = blockIdx.x % 12;             // p*4 + og
  int p = sub >> 2, og = sub & 3;
  int ob = og * 8;
  int tvIdx = tile * 256 + threadIdx.x;   // 0..25599
  int n = tvIdx / TV, tv = tvIdx % TV;

  const float* W; const float* B;
  if (p == 0)      { W = Wv; B = bv; }
  else if (p == 1) { W = Wk; B = bk; }
  else             { W = Wq; B = bq; }

  float acc[8];
#pragma unroll
  for (int j = 0; j < 8; ++j) acc[j] = B[ob + j];

  const float* xp = x + (size_t)n * CC * TV + tv;
#pragma unroll 16
  for (int c = 0; c < CC; ++c) {
    float xc = xp[c * TV];
#pragma unroll
    for (int j = 0; j < 8; ++j)
      acc[j] = fmaf(W[(ob + j) * CC + c], xc, acc[j]);
  }

  if (p == 0) {                           // v_x -> transposed
#pragma unroll
    for (int j = 0; j < 8; ++j)
      VTb[(n * ICH + ob + j) * TV + tv] = (__bf16)acc[j];
  } else {
    bf16x8 t;
#pragma unroll
    for (int j = 0; j < 8; ++j) t[j] = (__bf16)acc[j];
    int base = (n * TV + tv) * ICH + ob;
    if (p == 1) *(bf16x8*)(Qb + base) = t;   // k_x -> attention rows
    else        *(bf16x8*)(Kb + base) = t;   // q_x -> attention cols
  }
}

// ---------------------------------------------------------------------------
// K2: MFMA flash attention (bf16, single-slice Pbuf, 2 m-tiles/wave, XCD
// swizzle, V prefetched above the LDS wait) + fused BN-stats epilogue with
// 4-WAY PARALLEL MERGE: wave w merges output-group w (b128 publish/reads)
// and writes its own quarter of P / Pl -- no single-wave serial tail.
// LDS union 31,744 B -> 5 blocks/CU. Per-block partials to private GSP slot.
// Grid = NB*50 = 800. P stored bf16.
// ---------------------------------------------------------------------------
__global__ __launch_bounds__(256) void attn_kernel(
    const __bf16* __restrict__ Qb, const __bf16* __restrict__ Kb,
    const __bf16* __restrict__ VTb, __bf16* __restrict__ P,
    const float* __restrict__ Wt, const float* __restrict__ bt,
    float* __restrict__ GSP) {
  __shared__ float smem_f[7936];             // 31,744 B union arena
  int b = blockIdx.x;
  int r8 = b & 7, qq = b >> 3;               // qq in [0,100)
  int n = r8 * 2 + (qq >= 50 ? 1 : 0);
  int rowTile = (qq >= 50) ? qq - 50 : qq;
  int row0 = rowTile * 32;

  int w = threadIdx.x >> 6;
  int lane = threadIdx.x & 63;
  int m = lane & 15, q = lane >> 4;

  // main-loop Pbuf: per wave 2 tiles x 16 x 72 bf16 = 2304 elem (4608 B)
  __bf16* Pw = (__bf16*)smem_f + w * 2304;

  const __bf16* Qn = Qb  + (size_t)n * TV * ICH;
  const __bf16* Kn = Kb  + (size_t)n * TV * ICH;
  const __bf16* Vn = VTb + (size_t)n * ICH * TV;

  bf16x8 aQ0 = *(const bf16x8*)(Qn + (row0 + m) * ICH + q * 8);
  bf16x8 aQ1 = *(const bf16x8*)(Qn + (row0 + 16 + m) * ICH + q * 8);

  f32x4 o00 = {0.f,0.f,0.f,0.f}, o01 = {0.f,0.f,0.f,0.f};
  f32x4 o10 = {0.f,0.f,0.f,0.f}, o11 = {0.f,0.f,0.f,0.f};
  f32x4 ls0 = {0.f,0.f,0.f,0.f}, ls1 = {0.f,0.f,0.f,0.f};
  const f32x4 zero = {0.f,0.f,0.f,0.f};

  int nch = (w == 3) ? 7 : 6;                // wave w: chunks {4j + (3-w)}

  for (int j = 0; j < nch; ++j) {
    int s0 = (4 * j + (3 - w)) * 64;
    // ---- QK^T: 4 subtiles of 16 s; shared bK feeds both m-tiles ----
#pragma unroll
    for (int st = 0; st < 4; ++st) {
      bf16x8 bK = *(const bf16x8*)(Kn + (s0 + st * 16 + m) * ICH + q * 8);
      f32x4 a0 = __builtin_amdgcn_mfma_f32_16x16x32_bf16(aQ0, bK, zero, 0, 0, 0);
      f32x4 a1 = __builtin_amdgcn_mfma_f32_16x16x32_bf16(aQ1, bK, zero, 0, 0, 0);
#pragma unroll
      for (int r = 0; r < 4; ++r) {
        float e0 = __expf(a0[r]); ls0[r] += e0;
        float e1 = __expf(a1[r]); ls1[r] += e1;
        Pw[(q * 4 + r) * 72 + st * 16 + m]        = (__bf16)e0;
        Pw[1152 + (q * 4 + r) * 72 + st * 16 + m] = (__bf16)e1;
      }
    }
    // prefetch V fragments (independent of LDS) above the wait
    bf16x8 pV[2][2];
#pragma unroll
    for (int kc = 0; kc < 2; ++kc)
#pragma unroll
      for (int ict = 0; ict < 2; ++ict)
        pV[kc][ict] = *(const bf16x8*)(Vn + (ict * 16 + m) * TV + s0 + kc * 32 + q * 8);
    // in-wave DS write->read ordering
    asm volatile("s_waitcnt lgkmcnt(0)" ::: "memory");
    // ---- P*V: 2 k-chunks of 32 s ----
#pragma unroll
    for (int kc = 0; kc < 2; ++kc) {
      bf16x8 aP0 = *(const bf16x8*)(Pw + m * 72 + kc * 32 + q * 8);
      bf16x8 aP1 = *(const bf16x8*)(Pw + 1152 + m * 72 + kc * 32 + q * 8);
      o00 = __builtin_amdgcn_mfma_f32_16x16x32_bf16(aP0, pV[kc][0], o00, 0, 0, 0);
      o10 = __builtin_amdgcn_mfma_f32_16x16x32_bf16(aP1, pV[kc][0], o10, 0, 0, 0);
      o01 = __builtin_amdgcn_mfma_f32_16x16x32_bf16(aP0, pV[kc][1], o01, 0, 0, 0);
      o11 = __builtin_amdgcn_mfma_f32_16x16x32_bf16(aP1, pV[kc][1], o11, 0, 0, 0);
    }
  }

  // row sums: reduce over the 16 m-lanes (C-layout rows live on fixed q)
#pragma unroll
  for (int mask = 1; mask <= 8; mask <<= 1) {
#pragma unroll
    for (int r = 0; r < 4; ++r) {
      ls0[r] += __shfl_xor(ls0[r], mask, 64);
      ls1[r] += __shfl_xor(ls1[r], mask, 64);
    }
  }

  // ---- epilogue arena (aliases Pbuf, which is dead after the barrier) ----
  float* pub = smem_f;                       // [4 waves][64 lanes][24]
  float* Pl  = smem_f + 6144;                // [32][36] normalized P tile
  float* red = smem_f + 7296;                // [4 waves][128]

  __syncthreads();
  f32x4* mp = (f32x4*)(pub + (w * 64 + lane) * 24);
  mp[0] = o00; mp[1] = o01; mp[2] = o10; mp[3] = o11;
  mp[4] = ls0; mp[5] = ls1;
  __syncthreads();

  // parallel merge: wave w owns group w; ls0 for w<2, ls1 for w>=2.
  {
    int lsIdx = 4 + (w >> 1);
    const f32x4* p0 = (const f32x4*)(pub + lane * 24);
    f32x4 osum = p0[w];
    f32x4 lsum = p0[lsIdx];
#pragma unroll
    for (int ww = 1; ww < 4; ++ww) {
      const f32x4* pp = (const f32x4*)(pub + (ww * 64 + lane) * 24);
      f32x4 ov = pp[w], lv = pp[lsIdx];
#pragma unroll
      for (int r = 0; r < 4; ++r) { osum[r] += ov[r]; lsum[r] += lv[r]; }
    }
    int tile = w >> 1, colh = (w & 1) * 16;
#pragma unroll
    for (int r = 0; r < 4; ++r) {
      float p = osum[r] / lsum[r];
      int row = tile * 16 + q * 4 + r;
      P[(n * TV + row0 + row) * ICH + colh + m] = (__bf16)p;
      Pl[row * 36 + colh + m] = p;
    }
  }
  __syncthreads();

  // ---- fused BN stats: thread (c = t&63, rows w*8..w*8+7) 64ch dot.
  // Pl reads are wave-uniform b128 broadcasts (stride 36 -> 16B-aligned).
  int c = threadIdx.x & 63;
  float wr[ICH];
#pragma unroll
  for (int i = 0; i < ICH; ++i) wr[i] = Wt[c * ICH + i];
  float bc = bt[c];
  float sy = 0.f, sy2 = 0.f;
#pragma unroll
  for (int rr = 0; rr < 8; ++rr) {
    const f32x4* pr = (const f32x4*)(Pl + (w * 8 + rr) * 36);
    float y = bc;
#pragma unroll
    for (int u = 0; u < 8; ++u) {
      f32x4 pv = pr[u];
#pragma unroll
      for (int k = 0; k < 4; ++k) y = fmaf(wr[u * 4 + k], pv[k], y);
    }
    sy += y; sy2 += y * y;
  }
  red[w * 128 + c]      = sy;
  red[w * 128 + 64 + c] = sy2;
  __syncthreads();
  if (threadIdx.x < 128) {
    int t = threadIdx.x;
    float s = red[t] + red[128 + t] + red[256 + t] + red[384 + t];
    GSP[(size_t)blockIdx.x * 128 + t] = s;   // private slot, no atomics
  }
}

// ---------------------------------------------------------------------------
// K3: sum GSP[800][128] -> BN scale/shift SS, plus ChannelGate MLP -> GATE.
// 1 block, 256 threads (2-way split over the 800 slots).
// AVG lives in d_out (overwritten later by apply).
// ---------------------------------------------------------------------------
__global__ __launch_bounds__(256) void finalize_stats(
    const float* __restrict__ GSP, const float* __restrict__ gamma,
    const float* __restrict__ beta, const float* __restrict__ AVG,
    const float* __restrict__ W1, const float* __restrict__ b1,
    const float* __restrict__ W2, const float* __restrict__ b2,
    float* __restrict__ SS, float* __restrict__ GATE) {
  int t = threadIdx.x;
  __shared__ float acc2[2][128];
  __shared__ float shs[128];
  __shared__ float sh[NB][4];
  {
    int c = t & 127, half = t >> 7;
    float s = 0.f;
    for (int b = half * 400; b < half * 400 + 400; ++b)
      s += GSP[(size_t)b * 128 + c];
    acc2[half][c] = s;
  }
  __syncthreads();
  if (t < 128) shs[t] = acc2[0][t] + acc2[1][t];
  __syncthreads();
  if (t < 64) {
    int c = t;
    float mean = shs[c] * (1.f / (float)NTV);
    float var  = shs[64 + c] * (1.f / (float)NTV) - mean * mean;
    float scale = rsqrtf(var + 1e-5f) * gamma[c];
    SS[c] = scale;
    SS[64 + c] = beta[c] - mean * scale;
    int n = t >> 2, jj = t & 3;
    float h = b1[jj];
    for (int c2 = 0; c2 < CC; ++c2)
      h = fmaf(W1[jj * CC + c2], AVG[n * CC + c2], h);
    sh[n][jj] = fmaxf(h, 0.f);
  }
  __syncthreads();
#pragma unroll
  for (int u = 0; u < 4; ++u) {
    int idx = t * 4 + u;
    int n = idx >> 6, c = idx & 63;
    float g = b2[c];
#pragma unroll
    for (int jj = 0; jj < 4; ++jj) g = fmaf(W2[c * 4 + jj], sh[n][jj], g);
    GATE[idx] = 1.f / (1.f + __expf(-g));
  }
}

// ---------------------------------------------------------------------------
// K4: recompute y for 8 channels from bf16 P, apply BN + gate + residual.
// Grid 800 = cg(8 ch)*100 + tb.
// ---------------------------------------------------------------------------
__global__ __launch_bounds__(256) void apply_kernel(
    const __bf16* __restrict__ P, const float* __restrict__ Wt,
    const float* __restrict__ bt, const float* __restrict__ SS,
    const float* __restrict__ gate, const float* __restrict__ x,
    float* __restrict__ out) {
  int cg = blockIdx.x / 100;
  int tb = blockIdx.x % 100;
  int tvIdx = tb * 256 + threadIdx.x;
  int n = tvIdx / TV, tv = tvIdx % TV;

  float f[ICH];
  const bf16x8* pp = (const bf16x8*)(P + ((size_t)(n * TV + tv)) * ICH);
#pragma unroll
  for (int u = 0; u < 4; ++u) {
    bf16x8 v = pp[u];
#pragma unroll
    for (int j = 0; j < 8; ++j) f[u * 8 + j] = (float)v[j];
  }

#pragma unroll
  for (int j = 0; j < 8; ++j) {
    int c = cg * 8 + j;
    float y = bt[c];
#pragma unroll
    for (int i = 0; i < ICH; ++i) y = fmaf(Wt[c * ICH + i], f[i], y);
    size_t idx = ((size_t)(n * CC + c)) * TV + tv;
    out[idx] = gate[n * CC + c] * fmaf(y, SS[c], SS[64 + c]) + x[idx];
  }
}

// ---------------------------------------------------------------------------
extern "C" void kernel_launch(void* const* d_in, const int* in_sizes, int n_in,
                              void* d_out, int out_size, void* d_ws, size_t ws_size,
                              hipStream_t stream) {
  const float* x     = (const float*)d_in[0];
  const float* Wv    = (const float*)d_in[1];
  const float* bv    = (const float*)d_in[2];
  const float* Wk    = (const float*)d_in[3];
  const float* bk    = (const float*)d_in[4];
  const float* Wq    = (const float*)d_in[5];
  const float* bq    = (const float*)d_in[6];
  const float* Wt    = (const float*)d_in[7];
  const float* bt    = (const float*)d_in[8];
  const float* gamma = (const float*)d_in[9];
  const float* beta  = (const float*)d_in[10];
  const float* W1    = (const float*)d_in[11];
  const float* b1    = (const float*)d_in[12];
  const float* W2    = (const float*)d_in[13];
  const float* b2    = (const float*)d_in[14];
  float* out = (float*)d_out;
  char* ws = (char*)d_ws;

  // workspace layout (bytes) — total ~7.0 MB
  const size_t E = 819200;                    // N*TV*ICH elements
  __bf16* Qb  = (__bf16*)(ws);                // 2E bytes
  __bf16* Kb  = (__bf16*)(ws + 2*E);          // 2E bytes
  __bf16* VTb = (__bf16*)(ws + 4*E);          // 2E bytes
  __bf16* Pb  = (__bf16*)(ws + 6*E);          // 2E bytes
  float*  GSP = (float*) (ws + 8*E);          // 409600 B per-block partials
  float*  SS  = (float*) (ws + 8*E + 409600); // 512 B
  float*  GATE= (float*) (ws + 8*E + 410112); // 4096 B
  float*  AVG = out;   // scratch: fully overwritten by apply_kernel

  proj_gate_kernel<<<1264, 256, 0, stream>>>(x, Wv, bv, Wk, bk, Wq, bq,
                                             Qb, Kb, VTb, AVG);
  attn_kernel<<<NB * 50, 256, 0, stream>>>(Qb, Kb, VTb, Pb, Wt, bt, GSP);
  finalize_stats<<<1, 256, 0, stream>>>(GSP, gamma, beta, AVG,
                                        W1, b1, W2, b2, SS, GATE);
  apply_kernel<<<800, 256, 0, stream>>>(Pb, Wt, bt, SS, GATE, x, out);
}

// Round 11
// 141.640 us; speedup vs baseline: 1.4065x; 1.0078x over previous
//
#include <hip/hip_runtime.h>
#include <hip/hip_bf16.h>
#include <math.h>

// Problem constants
#define NB   16      // batch
#define CC   64      // channels
#define ICH  32      // inter channels
#define TV   1600    // T*V = 64*25
#define NTV  (NB*TV) // 25600

typedef __bf16 bf16x8 __attribute__((ext_vector_type(8)));
typedef float  f32x4  __attribute__((ext_vector_type(4)));

// ---------------------------------------------------------------------------
// K1: 1x1 conv projections, p-split (12-way: 3 proj x 4 o-groups) for high
// TLP. Blocks 0..1199: proj. 1200..1263: ChannelGate avg.
//  Qb = k_x [N,TV,32]   Kb = q_x [N,TV,32]   VTb = v_x^T [N,32,TV]
// ---------------------------------------------------------------------------
__global__ __launch_bounds__(256) void proj_gate_kernel(
    const float* __restrict__ x,
    const float* __restrict__ Wv, const float* __restrict__ bv,
    const float* __restrict__ Wk, const float* __restrict__ bk,
    const float* __restrict__ Wq, const float* __restrict__ bq,
    __bf16* __restrict__ Qb, __bf16* __restrict__ Kb,
    __bf16* __restrict__ VTb, float* __restrict__ AVG) {
  if (blockIdx.x >= 1200) {
    // ---- ChannelGate phase 1: per-(n, c) mean over TV ----
    int b = blockIdx.x - 1200;
    int n = b >> 2, cq = b & 3;
    int c16 = threadIdx.x >> 4, l = threadIdx.x & 15;
    int c = cq * 16 + c16;
    const float4* xp = (const float4*)(x + ((size_t)n * CC + c) * TV) + l;
    float s = 0.f;
#pragma unroll
    for (int i = 0; i < 25; ++i) {
      float4 v = xp[i * 16];
      s += v.x + v.y + v.z + v.w;
    }
#pragma unroll
    for (int off = 8; off >= 1; off >>= 1) s += __shfl_down(s, off, 16);
    if (l == 0) AVG[n * CC + c] = s * (1.0f / (float)TV);
    return;
  }

  int tile = blockIdx.x / 12;
  int sub  = blockIdx.x % 12;             // p*4 + og
  int p = sub >> 2, og = sub & 3;
  int ob = og * 8;
  int tvIdx = tile * 256 + threadIdx.x;   // 0..25599
  int n = tvIdx / TV, tv = tvIdx % TV;

  const float* W; const float* B;
  if (p == 0)      { W = Wv; B = bv; }
  else if (p == 1) { W = Wk; B = bk; }
  else             { W = Wq; B = bq; }

  float acc[8];
#pragma unroll
  for (int j = 0; j < 8; ++j) acc[j] = B[ob + j];

  const float* xp = x + (size_t)n * CC * TV + tv;
#pragma unroll 16
  for (int c = 0; c < CC; ++c) {
    float xc = xp[c * TV];
#pragma unroll
    for (int j = 0; j < 8; ++j)
      acc[j] = fmaf(W[(ob + j) * CC + c], xc, acc[j]);
  }

  if (p == 0) {                           // v_x -> transposed
#pragma unroll
    for (int j = 0; j < 8; ++j)
      VTb[(n * ICH + ob + j) * TV + tv] = (__bf16)acc[j];
  } else {
    bf16x8 t;
#pragma unroll
    for (int j = 0; j < 8; ++j) t[j] = (__bf16)acc[j];
    int base = (n * TV + tv) * ICH + ob;
    if (p == 1) *(bf16x8*)(Qb + base) = t;   // k_x -> attention rows
    else        *(bf16x8*)(Kb + base) = t;   // q_x -> attention cols
  }
}

// ---------------------------------------------------------------------------
// K2: MFMA flash attention (bf16, 2 m-tiles/wave, XCD swizzle) with FULL
// register pipelining: chunk j+1's K fragments AND chunk j's V fragments are
// issued before the lgkmcnt clobber, so no global-load latency sits on the
// post-wait critical path. Fused BN-stats epilogue with 4-way parallel
// merge. LDS 31,744 B. Per-block partials to private GSP slot (no atomics).
// Grid = NB*50 = 800. P stored bf16.
// ---------------------------------------------------------------------------
__global__ __launch_bounds__(256) void attn_kernel(
    const __bf16* __restrict__ Qb, const __bf16* __restrict__ Kb,
    const __bf16* __restrict__ VTb, __bf16* __restrict__ P,
    const float* __restrict__ Wt, const float* __restrict__ bt,
    float* __restrict__ GSP) {
  __shared__ float smem_f[7936];             // 31,744 B union arena
  int b = blockIdx.x;
  int r8 = b & 7, qq = b >> 3;               // qq in [0,100)
  int n = r8 * 2 + (qq >= 50 ? 1 : 0);
  int rowTile = (qq >= 50) ? qq - 50 : qq;
  int row0 = rowTile * 32;

  int w = threadIdx.x >> 6;
  int lane = threadIdx.x & 63;
  int m = lane & 15, q = lane >> 4;

  // main-loop Pbuf: per wave 2 tiles x 16 x 72 bf16 = 2304 elem (4608 B)
  __bf16* Pw = (__bf16*)smem_f + w * 2304;

  const __bf16* Qn = Qb  + (size_t)n * TV * ICH;
  const __bf16* Kn = Kb  + (size_t)n * TV * ICH;
  const __bf16* Vn = VTb + (size_t)n * ICH * TV;

  bf16x8 aQ0 = *(const bf16x8*)(Qn + (row0 + m) * ICH + q * 8);
  bf16x8 aQ1 = *(const bf16x8*)(Qn + (row0 + 16 + m) * ICH + q * 8);

  f32x4 o00 = {0.f,0.f,0.f,0.f}, o01 = {0.f,0.f,0.f,0.f};
  f32x4 o10 = {0.f,0.f,0.f,0.f}, o11 = {0.f,0.f,0.f,0.f};
  f32x4 ls0 = {0.f,0.f,0.f,0.f}, ls1 = {0.f,0.f,0.f,0.f};
  const f32x4 zero = {0.f,0.f,0.f,0.f};

  int nch = (w == 3) ? 7 : 6;                // wave w: chunks {4j + (3-w)}

  // preload chunk 0's K fragments into registers
  bf16x8 bKc[4];
  {
    int s0 = (3 - w) * 64;
#pragma unroll
    for (int st = 0; st < 4; ++st)
      bKc[st] = *(const bf16x8*)(Kn + (s0 + st * 16 + m) * ICH + q * 8);
  }

  for (int j = 0; j < nch; ++j) {
    int s0 = (4 * j + (3 - w)) * 64;
    // ---- QK^T with in-register bK; shared bK feeds both m-tiles ----
#pragma unroll
    for (int st = 0; st < 4; ++st) {
      f32x4 a0 = __builtin_amdgcn_mfma_f32_16x16x32_bf16(aQ0, bKc[st], zero, 0, 0, 0);
      f32x4 a1 = __builtin_amdgcn_mfma_f32_16x16x32_bf16(aQ1, bKc[st], zero, 0, 0, 0);
#pragma unroll
      for (int r = 0; r < 4; ++r) {
        float e0 = __expf(a0[r]); ls0[r] += e0;
        float e1 = __expf(a1[r]); ls1[r] += e1;
        Pw[(q * 4 + r) * 72 + st * 16 + m]        = (__bf16)e0;
        Pw[1152 + (q * 4 + r) * 72 + st * 16 + m] = (__bf16)e1;
      }
    }
    // prefetch next chunk's K + this chunk's V (independent of LDS) BEFORE
    // the wait -- keeps all global latency off the post-wait critical path.
    int chn = 4 * (j + 1) + (3 - w);
    int s0n = (chn < 25 ? chn : 0) * 64;       // clamped, wave-uniform
    bf16x8 bKn[4], pV[2][2];
#pragma unroll
    for (int st = 0; st < 4; ++st)
      bKn[st] = *(const bf16x8*)(Kn + (s0n + st * 16 + m) * ICH + q * 8);
#pragma unroll
    for (int kc = 0; kc < 2; ++kc)
#pragma unroll
      for (int ict = 0; ict < 2; ++ict)
        pV[kc][ict] = *(const bf16x8*)(Vn + (ict * 16 + m) * TV + s0 + kc * 32 + q * 8);
    // in-wave DS write->read ordering
    asm volatile("s_waitcnt lgkmcnt(0)" ::: "memory");
    // ---- P*V: 2 k-chunks of 32 s ----
#pragma unroll
    for (int kc = 0; kc < 2; ++kc) {
      bf16x8 aP0 = *(const bf16x8*)(Pw + m * 72 + kc * 32 + q * 8);
      bf16x8 aP1 = *(const bf16x8*)(Pw + 1152 + m * 72 + kc * 32 + q * 8);
      o00 = __builtin_amdgcn_mfma_f32_16x16x32_bf16(aP0, pV[kc][0], o00, 0, 0, 0);
      o10 = __builtin_amdgcn_mfma_f32_16x16x32_bf16(aP1, pV[kc][0], o10, 0, 0, 0);
      o01 = __builtin_amdgcn_mfma_f32_16x16x32_bf16(aP0, pV[kc][1], o01, 0, 0, 0);
      o11 = __builtin_amdgcn_mfma_f32_16x16x32_bf16(aP1, pV[kc][1], o11, 0, 0, 0);
    }
#pragma unroll
    for (int st = 0; st < 4; ++st) bKc[st] = bKn[st];
  }

  // row sums: reduce over the 16 m-lanes (C-layout rows live on fixed q)
#pragma unroll
  for (int mask = 1; mask <= 8; mask <<= 1) {
#pragma unroll
    for (int r = 0; r < 4; ++r) {
      ls0[r] += __shfl_xor(ls0[r], mask, 64);
      ls1[r] += __shfl_xor(ls1[r], mask, 64);
    }
  }

  // ---- epilogue arena (aliases Pbuf, which is dead after the barrier) ----
  float* pub = smem_f;                       // [4 waves][64 lanes][24]
  float* Pl  = smem_f + 6144;                // [32][36] normalized P tile
  float* red = smem_f + 7296;                // [4 waves][128]

  __syncthreads();
  f32x4* mp = (f32x4*)(pub + (w * 64 + lane) * 24);
  mp[0] = o00; mp[1] = o01; mp[2] = o10; mp[3] = o11;
  mp[4] = ls0; mp[5] = ls1;
  __syncthreads();

  // parallel merge: wave w owns group w; ls0 for w<2, ls1 for w>=2.
  {
    int lsIdx = 4 + (w >> 1);
    const f32x4* p0 = (const f32x4*)(pub + lane * 24);
    f32x4 osum = p0[w];
    f32x4 lsum = p0[lsIdx];
#pragma unroll
    for (int ww = 1; ww < 4; ++ww) {
      const f32x4* pp = (const f32x4*)(pub + (ww * 64 + lane) * 24);
      f32x4 ov = pp[w], lv = pp[lsIdx];
#pragma unroll
      for (int r = 0; r < 4; ++r) { osum[r] += ov[r]; lsum[r] += lv[r]; }
    }
    int tile = w >> 1, colh = (w & 1) * 16;
#pragma unroll
    for (int r = 0; r < 4; ++r) {
      float p = osum[r] / lsum[r];
      int row = tile * 16 + q * 4 + r;
      P[(n * TV + row0 + row) * ICH + colh + m] = (__bf16)p;
      Pl[row * 36 + colh + m] = p;
    }
  }
  __syncthreads();

  // ---- fused BN stats: thread (c = t&63, rows w*8..w*8+7) 64ch dot.
  // Pl reads are wave-uniform b128 broadcasts (stride 36 -> 16B-aligned).
  int c = threadIdx.x & 63;
  float wr[ICH];
#pragma unroll
  for (int i = 0; i < ICH; ++i) wr[i] = Wt[c * ICH + i];
  float bc = bt[c];
  float sy = 0.f, sy2 = 0.f;
#pragma unroll
  for (int rr = 0; rr < 8; ++rr) {
    const f32x4* pr = (const f32x4*)(Pl + (w * 8 + rr) * 36);
    float y = bc;
#pragma unroll
    for (int u = 0; u < 8; ++u) {
      f32x4 pv = pr[u];
#pragma unroll
      for (int k = 0; k < 4; ++k) y = fmaf(wr[u * 4 + k], pv[k], y);
    }
    sy += y; sy2 += y * y;
  }
  red[w * 128 + c]      = sy;
  red[w * 128 + 64 + c] = sy2;
  __syncthreads();
  if (threadIdx.x < 128) {
    int t = threadIdx.x;
    float s = red[t] + red[128 + t] + red[256 + t] + red[384 + t];
    GSP[(size_t)blockIdx.x * 128 + t] = s;   // private slot, no atomics
  }
}

// ---------------------------------------------------------------------------
// K3: sum GSP[800][128] -> BN scale/shift SS, plus ChannelGate MLP -> GATE.
// 1 block, 256 threads (2-way split over the 800 slots).
// AVG lives in d_out (overwritten later by apply).
// ---------------------------------------------------------------------------
__global__ __launch_bounds__(256) void finalize_stats(
    const float* __restrict__ GSP, const float* __restrict__ gamma,
    const float* __restrict__ beta, const float* __restrict__ AVG,
    const float* __restrict__ W1, const float* __restrict__ b1,
    const float* __restrict__ W2, const float* __restrict__ b2,
    float* __restrict__ SS, float* __restrict__ GATE) {
  int t = threadIdx.x;
  __shared__ float acc2[2][128];
  __shared__ float shs[128];
  __shared__ float sh[NB][4];
  {
    int c = t & 127, half = t >> 7;
    float s = 0.f;
    for (int b = half * 400; b < half * 400 + 400; ++b)
      s += GSP[(size_t)b * 128 + c];
    acc2[half][c] = s;
  }
  __syncthreads();
  if (t < 128) shs[t] = acc2[0][t] + acc2[1][t];
  __syncthreads();
  if (t < 64) {
    int c = t;
    float mean = shs[c] * (1.f / (float)NTV);
    float var  = shs[64 + c] * (1.f / (float)NTV) - mean * mean;
    float scale = rsqrtf(var + 1e-5f) * gamma[c];
    SS[c] = scale;
    SS[64 + c] = beta[c] - mean * scale;
    int n = t >> 2, jj = t & 3;
    float h = b1[jj];
    for (int c2 = 0; c2 < CC; ++c2)
      h = fmaf(W1[jj * CC + c2], AVG[n * CC + c2], h);
    sh[n][jj] = fmaxf(h, 0.f);
  }
  __syncthreads();
#pragma unroll
  for (int u = 0; u < 4; ++u) {
    int idx = t * 4 + u;
    int n = idx >> 6, c = idx & 63;
    float g = b2[c];
#pragma unroll
    for (int jj = 0; jj < 4; ++jj) g = fmaf(W2[c * 4 + jj], sh[n][jj], g);
    GATE[idx] = 1.f / (1.f + __expf(-g));
  }
}

// ---------------------------------------------------------------------------
// K4: recompute y for 8 channels from bf16 P, apply BN + gate + residual.
// Grid 800 = cg(8 ch)*100 + tb.
// ---------------------------------------------------------------------------
__global__ __launch_bounds__(256) void apply_kernel(
    const __bf16* __restrict__ P, const float* __restrict__ Wt,
    const float* __restrict__ bt, const float* __restrict__ SS,
    const float* __restrict__ gate, const float* __restrict__ x,
    float* __restrict__ out) {
  int cg = blockIdx.x / 100;
  int tb = blockIdx.x % 100;
  int tvIdx = tb * 256 + threadIdx.x;
  int n = tvIdx / TV, tv = tvIdx % TV;

  float f[ICH];
  const bf16x8* pp = (const bf16x8*)(P + ((size_t)(n * TV + tv)) * ICH);
#pragma unroll
  for (int u = 0; u < 4; ++u) {
    bf16x8 v = pp[u];
#pragma unroll
    for (int j = 0; j < 8; ++j) f[u * 8 + j] = (float)v[j];
  }

#pragma unroll
  for (int j = 0; j < 8; ++j) {
    int c = cg * 8 + j;
    float y = bt[c];
#pragma unroll
    for (int i = 0; i < ICH; ++i) y = fmaf(Wt[c * ICH + i], f[i], y);
    size_t idx = ((size_t)(n * CC + c)) * TV + tv;
    out[idx] = gate[n * CC + c] * fmaf(y, SS[c], SS[64 + c]) + x[idx];
  }
}

// ---------------------------------------------------------------------------
extern "C" void kernel_launch(void* const* d_in, const int* in_sizes, int n_in,
                              void* d_out, int out_size, void* d_ws, size_t ws_size,
                              hipStream_t stream) {
  const float* x     = (const float*)d_in[0];
  const float* Wv    = (const float*)d_in[1];
  const float* bv    = (const float*)d_in[2];
  const float* Wk    = (const float*)d_in[3];
  const float* bk    = (const float*)d_in[4];
  const float* Wq    = (const float*)d_in[5];
  const float* bq    = (const float*)d_in[6];
  const float* Wt    = (const float*)d_in[7];
  const float* bt    = (const float*)d_in[8];
  const float* gamma = (const float*)d_in[9];
  const float* beta  = (const float*)d_in[10];
  const float* W1    = (const float*)d_in[11];
  const float* b1    = (const float*)d_in[12];
  const float* W2    = (const float*)d_in[13];
  const float* b2    = (const float*)d_in[14];
  float* out = (float*)d_out;
  char* ws = (char*)d_ws;

  // workspace layout (bytes) — total ~7.0 MB
  const size_t E = 819200;                    // N*TV*ICH elements
  __bf16* Qb  = (__bf16*)(ws);                // 2E bytes
  __bf16* Kb  = (__bf16*)(ws + 2*E);          // 2E bytes
  __bf16* VTb = (__bf16*)(ws + 4*E);          // 2E bytes
  __bf16* Pb  = (__bf16*)(ws + 6*E);          // 2E bytes
  float*  GSP = (float*) (ws + 8*E);          // 409600 B per-block partials
  float*  SS  = (float*) (ws + 8*E + 409600); // 512 B
  float*  GATE= (float*) (ws + 8*E + 410112); // 4096 B
  float*  AVG = out;   // scratch: fully overwritten by apply_kernel

  proj_gate_kernel<<<1264, 256, 0, stream>>>(x, Wv, bv, Wk, bk, Wq, bq,
                                             Qb, Kb, VTb, AVG);
  attn_kernel<<<NB * 50, 256, 0, stream>>>(Qb, Kb, VTb, Pb, Wt, bt, GSP);
  finalize_stats<<<1, 256, 0, stream>>>(GSP, gamma, beta, AVG,
                                        W1, b1, W2, b2, SS, GATE);
  apply_kernel<<<800, 256, 0, stream>>>(Pb, Wt, bt, SS, GATE, x, out);
}

// Round 12
// 141.459 us; speedup vs baseline: 1.4083x; 1.0013x over previous
//
#include <hip/hip_runtime.h>
#include <hip/hip_bf16.h>
#include <math.h>

// Problem constants
#define NB   16      // batch
#define CC   64      // channels
#define ICH  32      // inter channels
#define TV   1600    // T*V = 64*25
#define NTV  (NB*TV) // 25600

typedef __bf16 bf16x8 __attribute__((ext_vector_type(8)));
typedef float  f32x4  __attribute__((ext_vector_type(4)));

// ---------------------------------------------------------------------------
// K1: 1x1 conv projections, p-split (12-way: 3 proj x 4 o-groups), XCD-
// SWIZZLED so all 12 blocks sharing an x-tile land on ONE XCD residue class
// (x tile then served 12x from that XCD's L2 instead of re-fetched by 8
// XCDs). Proj blocks 0..1247 (48 no-op), gate blocks 1248..1311.
//  Qb = k_x [N,TV,32]   Kb = q_x [N,TV,32]   VTb = v_x^T [N,32,TV]
// ---------------------------------------------------------------------------
__global__ __launch_bounds__(256) void proj_gate_kernel(
    const float* __restrict__ x,
    const float* __restrict__ Wv, const float* __restrict__ bv,
    const float* __restrict__ Wk, const float* __restrict__ bk,
    const float* __restrict__ Wq, const float* __restrict__ bq,
    __bf16* __restrict__ Qb, __bf16* __restrict__ Kb,
    __bf16* __restrict__ VTb, float* __restrict__ AVG) {
  if (blockIdx.x >= 1248) {
    // ---- ChannelGate phase 1: per-(n, c) mean over TV ----
    int b = blockIdx.x - 1248;
    int n = b >> 2, cq = b & 3;
    int c16 = threadIdx.x >> 4, l = threadIdx.x & 15;
    int c = cq * 16 + c16;
    const float4* xp = (const float4*)(x + ((size_t)n * CC + c) * TV) + l;
    float s = 0.f;
#pragma unroll
    for (int i = 0; i < 25; ++i) {
      float4 v = xp[i * 16];
      s += v.x + v.y + v.z + v.w;
    }
#pragma unroll
    for (int off = 8; off >= 1; off >>= 1) s += __shfl_down(s, off, 16);
    if (l == 0) AVG[n * CC + c] = s * (1.0f / (float)TV);
    return;
  }

  // XCD swizzle: XCD = blockIdx % 8; tile = r + 8g so all subs of a tile
  // share residue r -> same XCD.
  int r = blockIdx.x & 7;
  int i = blockIdx.x >> 3;               // 0..155
  int g = i / 12, sub = i % 12;          // sub = p*4 + og
  int tile = r + 8 * g;
  if (tile >= 100) return;               // 48 no-op blocks

  int p = sub >> 2, og = sub & 3;
  int ob = og * 8;
  int tvIdx = tile * 256 + threadIdx.x;  // 0..25599
  int n = tvIdx / TV, tv = tvIdx % TV;

  const float* W; const float* B;
  if (p == 0)      { W = Wv; B = bv; }
  else if (p == 1) { W = Wk; B = bk; }
  else             { W = Wq; B = bq; }

  float acc[8];
#pragma unroll
  for (int j = 0; j < 8; ++j) acc[j] = B[ob + j];

  const float* xp = x + (size_t)n * CC * TV + tv;
#pragma unroll 16
  for (int c = 0; c < CC; ++c) {
    float xc = xp[c * TV];
#pragma unroll
    for (int j = 0; j < 8; ++j)
      acc[j] = fmaf(W[(ob + j) * CC + c], xc, acc[j]);
  }

  if (p == 0) {                           // v_x -> transposed
#pragma unroll
    for (int j = 0; j < 8; ++j)
      VTb[(n * ICH + ob + j) * TV + tv] = (__bf16)acc[j];
  } else {
    bf16x8 t;
#pragma unroll
    for (int j = 0; j < 8; ++j) t[j] = (__bf16)acc[j];
    int base = (n * TV + tv) * ICH + ob;
    if (p == 1) *(bf16x8*)(Qb + base) = t;   // k_x -> attention rows
    else        *(bf16x8*)(Kb + base) = t;   // q_x -> attention cols
  }
}

// ---------------------------------------------------------------------------
// K2: MFMA flash attention (bf16, 2 m-tiles/wave, XCD swizzle, K+V register
// pipelining) + fused BN-stats epilogue with 4-way parallel merge.
// Wave chunk-count imbalance (7 vs 6) rotated per block. LDS 31,744 B.
// Per-block partials to private GSP slot (no atomics). Grid = NB*50 = 800.
// ---------------------------------------------------------------------------
__global__ __launch_bounds__(256) void attn_kernel(
    const __bf16* __restrict__ Qb, const __bf16* __restrict__ Kb,
    const __bf16* __restrict__ VTb, __bf16* __restrict__ P,
    const float* __restrict__ Wt, const float* __restrict__ bt,
    float* __restrict__ GSP) {
  __shared__ float smem_f[7936];             // 31,744 B union arena
  int b = blockIdx.x;
  int r8 = b & 7, qq = b >> 3;               // qq in [0,100)
  int n = r8 * 2 + (qq >= 50 ? 1 : 0);
  int rowTile = (qq >= 50) ? qq - 50 : qq;
  int row0 = rowTile * 32;

  int w = threadIdx.x >> 6;
  int lane = threadIdx.x & 63;
  int m = lane & 15, q = lane >> 4;

  // main-loop Pbuf: per wave 2 tiles x 16 x 72 bf16 = 2304 elem (4608 B)
  __bf16* Pw = (__bf16*)smem_f + w * 2304;

  const __bf16* Qn = Qb  + (size_t)n * TV * ICH;
  const __bf16* Kn = Kb  + (size_t)n * TV * ICH;
  const __bf16* Vn = VTb + (size_t)n * ICH * TV;

  bf16x8 aQ0 = *(const bf16x8*)(Qn + (row0 + m) * ICH + q * 8);
  bf16x8 aQ1 = *(const bf16x8*)(Qn + (row0 + 16 + m) * ICH + q * 8);

  f32x4 o00 = {0.f,0.f,0.f,0.f}, o01 = {0.f,0.f,0.f,0.f};
  f32x4 o10 = {0.f,0.f,0.f,0.f}, o11 = {0.f,0.f,0.f,0.f};
  f32x4 ls0 = {0.f,0.f,0.f,0.f}, ls1 = {0.f,0.f,0.f,0.f};
  const f32x4 zero = {0.f,0.f,0.f,0.f};

  // chunk offset for this wave, rotated per block so the extra (7th) chunk
  // (offset 0) moves between waves across blocks.
  int ow = (w + b) & 3;                      // offset residue; 0 -> 7 chunks
  int nch = (ow == 0) ? 7 : 6;

  // preload chunk 0's K fragments into registers
  bf16x8 bKc[4];
  {
    int s0 = ow * 64;
#pragma unroll
    for (int st = 0; st < 4; ++st)
      bKc[st] = *(const bf16x8*)(Kn + (s0 + st * 16 + m) * ICH + q * 8);
  }

  for (int j = 0; j < nch; ++j) {
    int s0 = (4 * j + ow) * 64;
    // ---- QK^T with in-register bK; shared bK feeds both m-tiles ----
#pragma unroll
    for (int st = 0; st < 4; ++st) {
      f32x4 a0 = __builtin_amdgcn_mfma_f32_16x16x32_bf16(aQ0, bKc[st], zero, 0, 0, 0);
      f32x4 a1 = __builtin_amdgcn_mfma_f32_16x16x32_bf16(aQ1, bKc[st], zero, 0, 0, 0);
#pragma unroll
      for (int r = 0; r < 4; ++r) {
        float e0 = __expf(a0[r]); ls0[r] += e0;
        float e1 = __expf(a1[r]); ls1[r] += e1;
        Pw[(q * 4 + r) * 72 + st * 16 + m]        = (__bf16)e0;
        Pw[1152 + (q * 4 + r) * 72 + st * 16 + m] = (__bf16)e1;
      }
    }
    // prefetch next chunk's K + this chunk's V BEFORE the wait
    int chn = 4 * (j + 1) + ow;
    int s0n = (chn < 25 ? chn : 0) * 64;       // clamped, wave-uniform
    bf16x8 bKn[4], pV[2][2];
#pragma unroll
    for (int st = 0; st < 4; ++st)
      bKn[st] = *(const bf16x8*)(Kn + (s0n + st * 16 + m) * ICH + q * 8);
#pragma unroll
    for (int kc = 0; kc < 2; ++kc)
#pragma unroll
      for (int ict = 0; ict < 2; ++ict)
        pV[kc][ict] = *(const bf16x8*)(Vn + (ict * 16 + m) * TV + s0 + kc * 32 + q * 8);
    // in-wave DS write->read ordering
    asm volatile("s_waitcnt lgkmcnt(0)" ::: "memory");
    // ---- P*V: 2 k-chunks of 32 s ----
#pragma unroll
    for (int kc = 0; kc < 2; ++kc) {
      bf16x8 aP0 = *(const bf16x8*)(Pw + m * 72 + kc * 32 + q * 8);
      bf16x8 aP1 = *(const bf16x8*)(Pw + 1152 + m * 72 + kc * 32 + q * 8);
      o00 = __builtin_amdgcn_mfma_f32_16x16x32_bf16(aP0, pV[kc][0], o00, 0, 0, 0);
      o10 = __builtin_amdgcn_mfma_f32_16x16x32_bf16(aP1, pV[kc][0], o10, 0, 0, 0);
      o01 = __builtin_amdgcn_mfma_f32_16x16x32_bf16(aP0, pV[kc][1], o01, 0, 0, 0);
      o11 = __builtin_amdgcn_mfma_f32_16x16x32_bf16(aP1, pV[kc][1], o11, 0, 0, 0);
    }
#pragma unroll
    for (int st = 0; st < 4; ++st) bKc[st] = bKn[st];
  }

  // row sums: reduce over the 16 m-lanes (C-layout rows live on fixed q)
#pragma unroll
  for (int mask = 1; mask <= 8; mask <<= 1) {
#pragma unroll
    for (int r = 0; r < 4; ++r) {
      ls0[r] += __shfl_xor(ls0[r], mask, 64);
      ls1[r] += __shfl_xor(ls1[r], mask, 64);
    }
  }

  // ---- epilogue arena (aliases Pbuf, which is dead after the barrier) ----
  float* pub = smem_f;                       // [4 waves][64 lanes][24]
  float* Pl  = smem_f + 6144;                // [32][36] normalized P tile
  float* red = smem_f + 7296;                // [4 waves][128]

  __syncthreads();
  f32x4* mp = (f32x4*)(pub + (w * 64 + lane) * 24);
  mp[0] = o00; mp[1] = o01; mp[2] = o10; mp[3] = o11;
  mp[4] = ls0; mp[5] = ls1;
  __syncthreads();

  // parallel merge: wave w owns group w; ls0 for w<2, ls1 for w>=2.
  {
    int lsIdx = 4 + (w >> 1);
    const f32x4* p0 = (const f32x4*)(pub + lane * 24);
    f32x4 osum = p0[w];
    f32x4 lsum = p0[lsIdx];
#pragma unroll
    for (int ww = 1; ww < 4; ++ww) {
      const f32x4* pp = (const f32x4*)(pub + (ww * 64 + lane) * 24);
      f32x4 ov = pp[w], lv = pp[lsIdx];
#pragma unroll
      for (int r = 0; r < 4; ++r) { osum[r] += ov[r]; lsum[r] += lv[r]; }
    }
    int tile = w >> 1, colh = (w & 1) * 16;
#pragma unroll
    for (int r = 0; r < 4; ++r) {
      float p = osum[r] / lsum[r];
      int row = tile * 16 + q * 4 + r;
      P[(n * TV + row0 + row) * ICH + colh + m] = (__bf16)p;
      Pl[row * 36 + colh + m] = p;
    }
  }
  __syncthreads();

  // ---- fused BN stats: thread (c = t&63, rows w*8..w*8+7) 64ch dot.
  // Pl reads are wave-uniform b128 broadcasts (stride 36 -> 16B-aligned).
  int c = threadIdx.x & 63;
  float wr[ICH];
#pragma unroll
  for (int i = 0; i < ICH; ++i) wr[i] = Wt[c * ICH + i];
  float bc = bt[c];
  float sy = 0.f, sy2 = 0.f;
#pragma unroll
  for (int rr = 0; rr < 8; ++rr) {
    const f32x4* pr = (const f32x4*)(Pl + (w * 8 + rr) * 36);
    float y = bc;
#pragma unroll
    for (int u = 0; u < 8; ++u) {
      f32x4 pv = pr[u];
#pragma unroll
      for (int k = 0; k < 4; ++k) y = fmaf(wr[u * 4 + k], pv[k], y);
    }
    sy += y; sy2 += y * y;
  }
  red[w * 128 + c]      = sy;
  red[w * 128 + 64 + c] = sy2;
  __syncthreads();
  if (threadIdx.x < 128) {
    int t = threadIdx.x;
    float s = red[t] + red[128 + t] + red[256 + t] + red[384 + t];
    GSP[(size_t)blockIdx.x * 128 + t] = s;   // private slot, no atomics
  }
}

// ---------------------------------------------------------------------------
// K3: sum GSP[800][128] -> BN scale/shift SS, plus ChannelGate MLP -> GATE.
// 1 block, 256 threads (2-way split over the 800 slots).
// AVG lives in d_out (overwritten later by apply).
// ---------------------------------------------------------------------------
__global__ __launch_bounds__(256) void finalize_stats(
    const float* __restrict__ GSP, const float* __restrict__ gamma,
    const float* __restrict__ beta, const float* __restrict__ AVG,
    const float* __restrict__ W1, const float* __restrict__ b1,
    const float* __restrict__ W2, const float* __restrict__ b2,
    float* __restrict__ SS, float* __restrict__ GATE) {
  int t = threadIdx.x;
  __shared__ float acc2[2][128];
  __shared__ float shs[128];
  __shared__ float sh[NB][4];
  {
    int c = t & 127, half = t >> 7;
    float s = 0.f;
    for (int b = half * 400; b < half * 400 + 400; ++b)
      s += GSP[(size_t)b * 128 + c];
    acc2[half][c] = s;
  }
  __syncthreads();
  if (t < 128) shs[t] = acc2[0][t] + acc2[1][t];
  __syncthreads();
  if (t < 64) {
    int c = t;
    float mean = shs[c] * (1.f / (float)NTV);
    float var  = shs[64 + c] * (1.f / (float)NTV) - mean * mean;
    float scale = rsqrtf(var + 1e-5f) * gamma[c];
    SS[c] = scale;
    SS[64 + c] = beta[c] - mean * scale;
    int n = t >> 2, jj = t & 3;
    float h = b1[jj];
    for (int c2 = 0; c2 < CC; ++c2)
      h = fmaf(W1[jj * CC + c2], AVG[n * CC + c2], h);
    sh[n][jj] = fmaxf(h, 0.f);
  }
  __syncthreads();
#pragma unroll
  for (int u = 0; u < 4; ++u) {
    int idx = t * 4 + u;
    int n = idx >> 6, c = idx & 63;
    float g = b2[c];
#pragma unroll
    for (int jj = 0; jj < 4; ++jj) g = fmaf(W2[c * 4 + jj], sh[n][jj], g);
    GATE[idx] = 1.f / (1.f + __expf(-g));
  }
}

// ---------------------------------------------------------------------------
// K4: recompute y for 8 channels from bf16 P, apply BN + gate + residual.
// XCD-SWIZZLED: the 8 cg-blocks sharing a P tv-tile land on one XCD residue
// (P tile L2-resident across its 8 readers). Grid 832 (32 no-op).
// ---------------------------------------------------------------------------
__global__ __launch_bounds__(256) void apply_kernel(
    const __bf16* __restrict__ P, const float* __restrict__ Wt,
    const float* __restrict__ bt, const float* __restrict__ SS,
    const float* __restrict__ gate, const float* __restrict__ x,
    float* __restrict__ out) {
  int r = blockIdx.x & 7;
  int i = blockIdx.x >> 3;              // 0..103
  int cg = i & 7, h = i >> 3;           // h in 0..12
  int tb = r + 8 * h;
  if (tb >= 100) return;                // 32 no-op blocks

  int tvIdx = tb * 256 + threadIdx.x;
  int n = tvIdx / TV, tv = tvIdx % TV;

  float f[ICH];
  const bf16x8* pp = (const bf16x8*)(P + ((size_t)(n * TV + tv)) * ICH);
#pragma unroll
  for (int u = 0; u < 4; ++u) {
    bf16x8 v = pp[u];
#pragma unroll
    for (int j = 0; j < 8; ++j) f[u * 8 + j] = (float)v[j];
  }

#pragma unroll
  for (int j = 0; j < 8; ++j) {
    int c = cg * 8 + j;
    float y = bt[c];
#pragma unroll
    for (int ii = 0; ii < ICH; ++ii) y = fmaf(Wt[c * ICH + ii], f[ii], y);
    size_t idx = ((size_t)(n * CC + c)) * TV + tv;
    out[idx] = gate[n * CC + c] * fmaf(y, SS[c], SS[64 + c]) + x[idx];
  }
}

// ---------------------------------------------------------------------------
extern "C" void kernel_launch(void* const* d_in, const int* in_sizes, int n_in,
                              void* d_out, int out_size, void* d_ws, size_t ws_size,
                              hipStream_t stream) {
  const float* x     = (const float*)d_in[0];
  const float* Wv    = (const float*)d_in[1];
  const float* bv    = (const float*)d_in[2];
  const float* Wk    = (const float*)d_in[3];
  const float* bk    = (const float*)d_in[4];
  const float* Wq    = (const float*)d_in[5];
  const float* bq    = (const float*)d_in[6];
  const float* Wt    = (const float*)d_in[7];
  const float* bt    = (const float*)d_in[8];
  const float* gamma = (const float*)d_in[9];
  const float* beta  = (const float*)d_in[10];
  const float* W1    = (const float*)d_in[11];
  const float* b1    = (const float*)d_in[12];
  const float* W2    = (const float*)d_in[13];
  const float* b2    = (const float*)d_in[14];
  float* out = (float*)d_out;
  char* ws = (char*)d_ws;

  // workspace layout (bytes) — total ~7.0 MB
  const size_t E = 819200;                    // N*TV*ICH elements
  __bf16* Qb  = (__bf16*)(ws);                // 2E bytes
  __bf16* Kb  = (__bf16*)(ws + 2*E);          // 2E bytes
  __bf16* VTb = (__bf16*)(ws + 4*E);          // 2E bytes
  __bf16* Pb  = (__bf16*)(ws + 6*E);          // 2E bytes
  float*  GSP = (float*) (ws + 8*E);          // 409600 B per-block partials
  float*  SS  = (float*) (ws + 8*E + 409600); // 512 B
  float*  GATE= (float*) (ws + 8*E + 410112); // 4096 B
  float*  AVG = out;   // scratch: fully overwritten by apply_kernel

  proj_gate_kernel<<<1312, 256, 0, stream>>>(x, Wv, bv, Wk, bk, Wq, bq,
                                             Qb, Kb, VTb, AVG);
  attn_kernel<<<NB * 50, 256, 0, stream>>>(Qb, Kb, VTb, Pb, Wt, bt, GSP);
  finalize_stats<<<1, 256, 0, stream>>>(GSP, gamma, beta, AVG,
                                        W1, b1, W2, b2, SS, GATE);
  apply_kernel<<<832, 256, 0, stream>>>(Pb, Wt, bt, SS, GATE, x, out);
}